// Round 2
// baseline (844.862 us; speedup 1.0000x reference)
//
#include <hip/hip_runtime.h>

#define IN_DIM  128
#define HID_DIM 64
#define OUT_DIM 32

// ---------------------------------------------------------------------------
// Detect whether edge_index is int64 or int32.
// Reading int32 data as uint64 packs two random values -> almost surely >= N.
__global__ void k_detect(const unsigned long long* p, long long nwords,
                         long long nnodes, int* flag) {
  if (blockIdx.x == 0 && threadIdx.x == 0) {
    int ok = 1;
    int cnt = (int)(nwords < 64 ? nwords : 64);
    for (int i = 0; i < cnt; ++i) {
      if (p[i] >= (unsigned long long)nnodes) { ok = 0; break; }
    }
    *flag = ok;  // 1 = int64, 0 = int32
  }
}

__device__ __forceinline__ long long load_idx(const void* p, long long i, int is64) {
  return is64 ? ((const long long*)p)[i] : (long long)((const int*)p)[i];
}

// ---------------------------------------------------------------------------
// deg[c] += 1 for every edge (self-loop handled analytically later).
__global__ __launch_bounds__(256) void k_deg(const void* eidx, long long E,
                                             float* __restrict__ deg,
                                             const int* __restrict__ flag) {
  long long e = (long long)blockIdx.x * 256 + threadIdx.x;
  if (e >= E) return;
  int f = *flag;
  long long c = load_idx(eidx, E + e, f);  // col = edge_index[1]
  atomicAdd(&deg[c], 1.0f);
}

// dinv[i] = rsqrt(deg[i] + 1)   (+1 = self-loop; always > 0)
__global__ __launch_bounds__(256) void k_dinv(float* __restrict__ deg, int N) {
  int i = blockIdx.x * 256 + threadIdx.x;
  if (i >= N) return;
  deg[i] = rsqrtf(deg[i] + 1.0f);
}

// ---------------------------------------------------------------------------
// xw1 = x @ W1   ([N,128] x [128,64]) ; W1 staged in LDS (32 KB).
// Block = 256 threads (4 waves); each block does 64 rows; lane = output col.
__global__ __launch_bounds__(256) void k_gemm1(const float* __restrict__ x,
                                               const float* __restrict__ W1,
                                               float* __restrict__ xw1, int N) {
  __shared__ float w[IN_DIM * HID_DIM];
  for (int i = threadIdx.x; i < IN_DIM * HID_DIM; i += 256) w[i] = W1[i];
  __syncthreads();
  const int lane = threadIdx.x & 63;
  const int wv   = threadIdx.x >> 6;
  const int base = blockIdx.x * 64;
  for (int r = wv; r < 64; r += 4) {
    int row = base + r;
    if (row >= N) break;
    const float4* xr = (const float4*)(x + (size_t)row * IN_DIM);
    float acc = 0.f;
#pragma unroll
    for (int k4 = 0; k4 < IN_DIM / 4; ++k4) {
      float4 xv = xr[k4];
      int k = k4 * 4;
      acc += xv.x * w[(k + 0) * HID_DIM + lane];
      acc += xv.y * w[(k + 1) * HID_DIM + lane];
      acc += xv.z * w[(k + 2) * HID_DIM + lane];
      acc += xv.w * w[(k + 3) * HID_DIM + lane];
    }
    xw1[(size_t)row * HID_DIM + lane] = acc;
  }
}

// ---------------------------------------------------------------------------
// Scatter layer 1: one wave per edge, lane j handles hidden dim j.
__global__ __launch_bounds__(256) void k_scatter1(const void* eidx, long long E,
                                                  const float* __restrict__ dinv,
                                                  const float* __restrict__ xw1,
                                                  float* __restrict__ agg,
                                                  const int* __restrict__ flag) {
  long long t = (long long)blockIdx.x * 256 + threadIdx.x;
  long long e = t >> 6;
  int j = (int)(t & 63);
  if (e >= E) return;
  int f = *flag;
  long long r = load_idx(eidx, e, f);
  long long c = load_idx(eidx, E + e, f);
  float nm = dinv[r] * dinv[c];
  atomicAdd(&agg[c * HID_DIM + j], nm * xw1[r * HID_DIM + j]);
}

// ---------------------------------------------------------------------------
// finalize layer1 + GEMM2 fused:
// h = relu(agg1 + dinv^2*xw1 + b1);  xw2 = h @ W2  (W2 in LDS, 8 KB)
// 32 threads per node (one per output col); 8 nodes per 256-thread block.
__global__ __launch_bounds__(256) void k_fin1gemm2(const float* __restrict__ agg1,
                                                   const float* __restrict__ xw1,
                                                   const float* __restrict__ dinv,
                                                   const float* __restrict__ b1,
                                                   const float* __restrict__ W2,
                                                   float* __restrict__ xw2, int N) {
  __shared__ float w2s[HID_DIM * OUT_DIM];
  for (int i = threadIdx.x; i < HID_DIM * OUT_DIM; i += 256) w2s[i] = W2[i];
  __syncthreads();
  int n  = blockIdx.x * 8 + (threadIdx.x >> 5);
  int jp = threadIdx.x & 31;
  if (n >= N) return;
  float dv = dinv[n];
  float d2 = dv * dv;
  const float* a  = agg1 + (size_t)n * HID_DIM;
  const float* xw = xw1  + (size_t)n * HID_DIM;
  float acc = 0.f;
#pragma unroll
  for (int j = 0; j < HID_DIM; ++j) {
    float h = a[j] + d2 * xw[j] + b1[j];
    h = h > 0.f ? h : 0.f;
    acc += h * w2s[j * OUT_DIM + jp];
  }
  xw2[(size_t)n * OUT_DIM + jp] = acc;
}

// ---------------------------------------------------------------------------
// Scatter layer 2: 32 lanes per edge (2 edges per wave), accumulate into d_out.
__global__ __launch_bounds__(256) void k_scatter2(const void* eidx, long long E,
                                                  const float* __restrict__ dinv,
                                                  const float* __restrict__ xw2,
                                                  float* __restrict__ out,
                                                  const int* __restrict__ flag) {
  long long t = (long long)blockIdx.x * 256 + threadIdx.x;
  long long e = t >> 5;
  int j = (int)(t & 31);
  if (e >= E) return;
  int f = *flag;
  long long r = load_idx(eidx, e, f);
  long long c = load_idx(eidx, E + e, f);
  float nm = dinv[r] * dinv[c];
  atomicAdd(&out[c * OUT_DIM + j], nm * xw2[r * OUT_DIM + j]);
}

// out = relu(out + dinv^2*xw2 + b2)   (in place on d_out)
__global__ __launch_bounds__(256) void k_fin2(float* __restrict__ out,
                                              const float* __restrict__ xw2,
                                              const float* __restrict__ dinv,
                                              const float* __restrict__ b2, int N) {
  long long t = (long long)blockIdx.x * 256 + threadIdx.x;
  if (t >= (long long)N * OUT_DIM) return;
  int n = (int)(t >> 5);
  int j = (int)(t & 31);
  float dv = dinv[n];
  float v = out[t] + dv * dv * xw2[t] + b2[j];
  out[t] = v > 0.f ? v : 0.f;
}

// ---------------------------------------------------------------------------
static inline size_t align256(size_t x) { return (x + 255) & ~(size_t)255; }

extern "C" void kernel_launch(void* const* d_in, const int* in_sizes, int n_in,
                              void* d_out, int out_size, void* d_ws, size_t ws_size,
                              hipStream_t stream) {
  const float* x   = (const float*)d_in[0];
  const float* W1  = (const float*)d_in[1];
  const float* b1  = (const float*)d_in[2];
  const float* W2  = (const float*)d_in[3];
  const float* b2  = (const float*)d_in[4];
  const void*  eidx = d_in[5];

  const int  N = in_sizes[0] / IN_DIM;          // 100000
  const long long E = (long long)in_sizes[5] / 2;  // 1600000

  // workspace layout
  char* ws = (char*)d_ws;
  size_t off = 0;
  int*   flag = (int*)(ws + off);   off += align256(sizeof(int));
  float* dinv = (float*)(ws + off); off += align256((size_t)N * 4);          // also deg accumulator
  float* xw1  = (float*)(ws + off); off += align256((size_t)N * HID_DIM * 4);
  float* agg1 = (float*)(ws + off); off += align256((size_t)N * HID_DIM * 4);
  float* xw2  = (float*)(ws + off); off += align256((size_t)N * OUT_DIM * 4);
  float* outf = (float*)d_out;

  // zero accumulators
  hipMemsetAsync(dinv, 0, (size_t)N * 4, stream);
  hipMemsetAsync(agg1, 0, (size_t)N * HID_DIM * 4, stream);
  hipMemsetAsync(outf, 0, (size_t)N * OUT_DIM * 4, stream);

  // dtype probe (int64 vs int32 edge_index)
  k_detect<<<1, 1, 0, stream>>>((const unsigned long long*)eidx, E, (long long)N, flag);

  // degrees -> dinv
  k_deg<<<(int)((E + 255) / 256), 256, 0, stream>>>(eidx, E, dinv, flag);
  k_dinv<<<(N + 255) / 256, 256, 0, stream>>>(dinv, N);

  // layer 1
  k_gemm1<<<(N + 63) / 64, 256, 0, stream>>>(x, W1, xw1, N);
  {
    long long threads = E * 64;
    k_scatter1<<<(int)((threads + 255) / 256), 256, 0, stream>>>(eidx, E, dinv, xw1, agg1, flag);
  }
  k_fin1gemm2<<<(N + 7) / 8, 256, 0, stream>>>(agg1, xw1, dinv, b1, W2, xw2, N);

  // layer 2
  {
    long long threads = E * 32;
    k_scatter2<<<(int)((threads + 255) / 256), 256, 0, stream>>>(eidx, E, dinv, xw2, outf, flag);
  }
  {
    long long total = (long long)N * OUT_DIM;
    k_fin2<<<(int)((total + 255) / 256), 256, 0, stream>>>(outf, xw2, dinv, b2, N);
  }
}

// Round 3
// 440.974 us; speedup vs baseline: 1.9159x; 1.9159x over previous
//
#include <hip/hip_runtime.h>

#define IN_DIM  128
#define HID_DIM 64
#define OUT_DIM 32
#define SCAN_CHUNK 1024   // elements per scan block (256 thr x 4)

// ---------------------------------------------------------------------------
// Detect whether edge_index is int64 or int32.
__global__ void k_detect(const unsigned long long* p, long long nwords,
                         long long nnodes, int* flag) {
  if (blockIdx.x == 0 && threadIdx.x == 0) {
    int ok = 1;
    int cnt = (int)(nwords < 64 ? nwords : 64);
    for (int i = 0; i < cnt; ++i) {
      if (p[i] >= (unsigned long long)nnodes) { ok = 0; break; }
    }
    *flag = ok;  // 1 = int64, 0 = int32
  }
}

__device__ __forceinline__ int load_idx(const void* p, long long i, int is64) {
  return is64 ? (int)((const long long*)p)[i] : ((const int*)p)[i];
}

// ---------------------------------------------------------------------------
// Histogram of destinations (self-loop handled analytically).
__global__ __launch_bounds__(256) void k_count(const void* eidx, long long E,
                                               int* __restrict__ cnt,
                                               const int* __restrict__ flag) {
  long long e = (long long)blockIdx.x * 256 + threadIdx.x;
  if (e >= E) return;
  int f = *flag;
  int c = load_idx(eidx, E + e, f);
  atomicAdd(&cnt[c], 1);
}

// dinv[i] = rsqrt(cnt[i] + 1)
__global__ __launch_bounds__(256) void k_dinv(const int* __restrict__ cnt,
                                              float* __restrict__ dinv, int N) {
  int i = blockIdx.x * 256 + threadIdx.x;
  if (i >= N) return;
  dinv[i] = rsqrtf((float)cnt[i] + 1.0f);
}

// ---------------------------------------------------------------------------
// 3-kernel exclusive scan of cnt[N] -> base[N]
__global__ __launch_bounds__(256) void k_blksum(const int* __restrict__ cnt, int N,
                                                int* __restrict__ partial) {
  __shared__ int s[256];
  int t = threadIdx.x;
  int i0 = blockIdx.x * SCAN_CHUNK + t * 4;
  int sum = 0;
#pragma unroll
  for (int k = 0; k < 4; ++k) { int i = i0 + k; if (i < N) sum += cnt[i]; }
  s[t] = sum; __syncthreads();
  for (int o = 128; o > 0; o >>= 1) { if (t < o) s[t] += s[t + o]; __syncthreads(); }
  if (t == 0) partial[blockIdx.x] = s[0];
}

__global__ __launch_bounds__(256) void k_scanpartial(int* __restrict__ partial, int nb) {
  __shared__ int s[256];
  int t = threadIdx.x;
  int own = (t < nb) ? partial[t] : 0;
  s[t] = own; __syncthreads();
  for (int o = 1; o < 256; o <<= 1) {
    int v = (t >= o) ? s[t - o] : 0;
    __syncthreads();
    s[t] += v;
    __syncthreads();
  }
  if (t < nb) partial[t] = s[t] - own;  // exclusive
}

__global__ __launch_bounds__(256) void k_base(const int* __restrict__ cnt,
                                              const int* __restrict__ partial, int N,
                                              int* __restrict__ base) {
  __shared__ int s[256];
  int t = threadIdx.x;
  int i0 = blockIdx.x * SCAN_CHUNK + t * 4;
  int v[4]; int sum = 0;
#pragma unroll
  for (int k = 0; k < 4; ++k) { int i = i0 + k; v[k] = (i < N) ? cnt[i] : 0; sum += v[k]; }
  s[t] = sum; __syncthreads();
  for (int o = 1; o < 256; o <<= 1) {
    int x = (t >= o) ? s[t - o] : 0;
    __syncthreads();
    s[t] += x;
    __syncthreads();
  }
  int off = partial[blockIdx.x] + (s[t] - sum);
#pragma unroll
  for (int k = 0; k < 4; ++k) {
    int i = i0 + k;
    if (i < N) { base[i] = off; off += v[k]; }
  }
}

// ---------------------------------------------------------------------------
// Fill CSR: entry[pos] = {src, norm}
__global__ __launch_bounds__(256) void k_fill(const void* eidx, long long E,
                                              const float* __restrict__ dinv,
                                              const int* __restrict__ base,
                                              int* __restrict__ cursor,
                                              int2* __restrict__ entry,
                                              const int* __restrict__ flag) {
  long long e = (long long)blockIdx.x * 256 + threadIdx.x;
  if (e >= E) return;
  int f = *flag;
  int r = load_idx(eidx, e, f);
  int c = load_idx(eidx, E + e, f);
  int pos = base[c] + atomicAdd(&cursor[c], 1);
  float nm = dinv[r] * dinv[c];
  entry[pos] = make_int2(r, __float_as_int(nm));
}

// ---------------------------------------------------------------------------
// xw1 = x @ W1   ([N,128] x [128,64]); W1 staged in LDS (32 KB).
__global__ __launch_bounds__(256) void k_gemm1(const float* __restrict__ x,
                                               const float* __restrict__ W1,
                                               float* __restrict__ xw1, int N) {
  __shared__ float w[IN_DIM * HID_DIM];
  for (int i = threadIdx.x; i < IN_DIM * HID_DIM; i += 256) w[i] = W1[i];
  __syncthreads();
  const int lane = threadIdx.x & 63;
  const int wv   = threadIdx.x >> 6;
  const int bb   = blockIdx.x * 64;
  for (int r = wv; r < 64; r += 4) {
    int row = bb + r;
    if (row >= N) break;
    const float4* xr = (const float4*)(x + (size_t)row * IN_DIM);
    float acc = 0.f;
#pragma unroll
    for (int k4 = 0; k4 < IN_DIM / 4; ++k4) {
      float4 xv = xr[k4];
      int k = k4 * 4;
      acc += xv.x * w[(k + 0) * HID_DIM + lane];
      acc += xv.y * w[(k + 1) * HID_DIM + lane];
      acc += xv.z * w[(k + 2) * HID_DIM + lane];
      acc += xv.w * w[(k + 3) * HID_DIM + lane];
    }
    xw1[(size_t)row * HID_DIM + lane] = acc;
  }
}

// ---------------------------------------------------------------------------
// gather layer 1 + relu + GEMM2 fused.
// 4 nodes per 256-thread block; 64 lanes per node (one per hidden dim).
// Epilogue: h staged in LDS, 32 threads/node compute h @ W2 -> xw2.
__global__ __launch_bounds__(256) void k_gather1(const int2* __restrict__ entry,
                                                 const int* __restrict__ base,
                                                 const int* __restrict__ cnt,
                                                 const float* __restrict__ dinv,
                                                 const float* __restrict__ xw1,
                                                 const float* __restrict__ b1,
                                                 const float* __restrict__ W2,
                                                 float* __restrict__ xw2, int N) {
  __shared__ float w2s[HID_DIM * OUT_DIM];  // 8 KB
  __shared__ float hs[4][HID_DIM];          // 1 KB
  for (int i = threadIdx.x; i < HID_DIM * OUT_DIM; i += 256) w2s[i] = W2[i];

  const int nl   = threadIdx.x >> 6;
  const int j    = threadIdx.x & 63;
  const int node = blockIdx.x * 4 + nl;

  float hv = 0.f;
  if (node < N) {
    int st  = base[node];
    int len = cnt[node];
    float a0 = 0.f, a1 = 0.f;
    int i = 0;
    for (; i + 1 < len; i += 2) {
      int2 e0 = entry[st + i];
      int2 e1 = entry[st + i + 1];
      a0 += __int_as_float(e0.y) * xw1[(size_t)e0.x * HID_DIM + j];
      a1 += __int_as_float(e1.y) * xw1[(size_t)e1.x * HID_DIM + j];
    }
    if (i < len) {
      int2 e0 = entry[st + i];
      a0 += __int_as_float(e0.y) * xw1[(size_t)e0.x * HID_DIM + j];
    }
    float dv = dinv[node];
    hv = a0 + a1 + dv * dv * xw1[(size_t)node * HID_DIM + j] + b1[j];
    hv = hv > 0.f ? hv : 0.f;
  }
  hs[nl][j] = hv;
  __syncthreads();

  if (threadIdx.x < 128) {
    int n2l   = threadIdx.x >> 5;
    int k     = threadIdx.x & 31;
    int node2 = blockIdx.x * 4 + n2l;
    if (node2 < N) {
      float acc = 0.f;
#pragma unroll
      for (int jj = 0; jj < HID_DIM; ++jj)
        acc += hs[n2l][jj] * w2s[jj * OUT_DIM + k];
      xw2[(size_t)node2 * OUT_DIM + k] = acc;
    }
  }
}

// ---------------------------------------------------------------------------
// gather layer 2 + relu, writes d_out directly. 8 nodes/block, 32 lanes/node.
__global__ __launch_bounds__(256) void k_gather2(const int2* __restrict__ entry,
                                                 const int* __restrict__ base,
                                                 const int* __restrict__ cnt,
                                                 const float* __restrict__ dinv,
                                                 const float* __restrict__ xw2,
                                                 const float* __restrict__ b2,
                                                 float* __restrict__ out, int N) {
  const int nl   = threadIdx.x >> 5;
  const int j    = threadIdx.x & 31;
  const int node = blockIdx.x * 8 + nl;
  if (node >= N) return;
  int st  = base[node];
  int len = cnt[node];
  float a0 = 0.f, a1 = 0.f;
  int i = 0;
  for (; i + 1 < len; i += 2) {
    int2 e0 = entry[st + i];
    int2 e1 = entry[st + i + 1];
    a0 += __int_as_float(e0.y) * xw2[(size_t)e0.x * OUT_DIM + j];
    a1 += __int_as_float(e1.y) * xw2[(size_t)e1.x * OUT_DIM + j];
  }
  if (i < len) {
    int2 e0 = entry[st + i];
    a0 += __int_as_float(e0.y) * xw2[(size_t)e0.x * OUT_DIM + j];
  }
  float dv = dinv[node];
  float v = a0 + a1 + dv * dv * xw2[(size_t)node * OUT_DIM + j] + b2[j];
  out[(size_t)node * OUT_DIM + j] = v > 0.f ? v : 0.f;
}

// ---------------------------------------------------------------------------
static inline size_t align256(size_t x) { return (x + 255) & ~(size_t)255; }

extern "C" void kernel_launch(void* const* d_in, const int* in_sizes, int n_in,
                              void* d_out, int out_size, void* d_ws, size_t ws_size,
                              hipStream_t stream) {
  const float* x   = (const float*)d_in[0];
  const float* W1  = (const float*)d_in[1];
  const float* b1  = (const float*)d_in[2];
  const float* W2  = (const float*)d_in[3];
  const float* b2  = (const float*)d_in[4];
  const void*  eidx = d_in[5];

  const int  N = in_sizes[0] / IN_DIM;             // 100000
  const long long E = (long long)in_sizes[5] / 2;  // 1600000
  const int  nb = (N + SCAN_CHUNK - 1) / SCAN_CHUNK;  // 98 (<=256)

  char* ws = (char*)d_ws;
  size_t off = 0;
  int*   flag    = (int*)(ws + off);   off += align256(sizeof(int));
  int*   cnt     = (int*)(ws + off);   off += align256((size_t)N * 4);
  float* dinv    = (float*)(ws + off); off += align256((size_t)N * 4);
  int*   base    = (int*)(ws + off);   off += align256((size_t)N * 4);
  int*   cursor  = (int*)(ws + off);   off += align256((size_t)N * 4);
  int*   partial = (int*)(ws + off);   off += align256(256 * 4);
  int2*  entry   = (int2*)(ws + off);  off += align256((size_t)E * 8);
  float* xw1     = (float*)(ws + off); off += align256((size_t)N * HID_DIM * 4);
  float* xw2     = (float*)(ws + off); off += align256((size_t)N * OUT_DIM * 4);
  float* outf    = (float*)d_out;

  hipMemsetAsync(cnt, 0, (size_t)N * 4, stream);
  hipMemsetAsync(cursor, 0, (size_t)N * 4, stream);

  k_detect<<<1, 1, 0, stream>>>((const unsigned long long*)eidx, E, (long long)N, flag);

  k_count<<<(int)((E + 255) / 256), 256, 0, stream>>>(eidx, E, cnt, flag);
  k_dinv<<<(N + 255) / 256, 256, 0, stream>>>(cnt, dinv, N);

  k_blksum<<<nb, 256, 0, stream>>>(cnt, N, partial);
  k_scanpartial<<<1, 256, 0, stream>>>(partial, nb);
  k_base<<<nb, 256, 0, stream>>>(cnt, partial, N, base);

  k_fill<<<(int)((E + 255) / 256), 256, 0, stream>>>(eidx, E, dinv, base, cursor, entry, flag);

  k_gemm1<<<(N + 63) / 64, 256, 0, stream>>>(x, W1, xw1, N);

  k_gather1<<<(N + 3) / 4, 256, 0, stream>>>(entry, base, cnt, dinv, xw1, b1, W2, xw2, N);

  k_gather2<<<(N + 7) / 8, 256, 0, stream>>>(entry, base, cnt, dinv, xw2, b2, outf, N);
}

// Round 4
// 367.444 us; speedup vs baseline: 2.2993x; 1.2001x over previous
//
#include <hip/hip_runtime.h>

#define IN_DIM  128
#define HID_DIM 64
#define OUT_DIM 32
#define SCAN_CHUNK 1024   // elements per scan block (256 thr x 4)

// ---------------------------------------------------------------------------
// Detect whether edge_index is int64 or int32.
__global__ void k_detect(const unsigned long long* p, long long nwords,
                         long long nnodes, int* flag) {
  if (blockIdx.x == 0 && threadIdx.x == 0) {
    int ok = 1;
    int cnt = (int)(nwords < 64 ? nwords : 64);
    for (int i = 0; i < cnt; ++i) {
      if (p[i] >= (unsigned long long)nnodes) { ok = 0; break; }
    }
    *flag = ok;  // 1 = int64, 0 = int32
  }
}

__device__ __forceinline__ int load_idx(const void* p, long long i, int is64) {
  return is64 ? (int)((const long long*)p)[i] : ((const int*)p)[i];
}

// ---------------------------------------------------------------------------
// Histogram of destinations (self-loop handled analytically).
__global__ __launch_bounds__(256) void k_count(const void* eidx, long long E,
                                               int* __restrict__ cnt,
                                               const int* __restrict__ flag) {
  long long e = (long long)blockIdx.x * 256 + threadIdx.x;
  if (e >= E) return;
  int f = *flag;
  int c = load_idx(eidx, E + e, f);
  atomicAdd(&cnt[c], 1);
}

// dinv[i] = rsqrt(cnt[i] + 1)
__global__ __launch_bounds__(256) void k_dinv(const int* __restrict__ cnt,
                                              float* __restrict__ dinv, int N) {
  int i = blockIdx.x * 256 + threadIdx.x;
  if (i >= N) return;
  dinv[i] = rsqrtf((float)cnt[i] + 1.0f);
}

// ---------------------------------------------------------------------------
// 3-kernel exclusive scan of cnt[N] -> base[N] (and cursor[N] = base[N])
__global__ __launch_bounds__(256) void k_blksum(const int* __restrict__ cnt, int N,
                                                int* __restrict__ partial) {
  __shared__ int s[256];
  int t = threadIdx.x;
  int i0 = blockIdx.x * SCAN_CHUNK + t * 4;
  int sum = 0;
#pragma unroll
  for (int k = 0; k < 4; ++k) { int i = i0 + k; if (i < N) sum += cnt[i]; }
  s[t] = sum; __syncthreads();
  for (int o = 128; o > 0; o >>= 1) { if (t < o) s[t] += s[t + o]; __syncthreads(); }
  if (t == 0) partial[blockIdx.x] = s[0];
}

__global__ __launch_bounds__(256) void k_scanpartial(int* __restrict__ partial, int nb) {
  __shared__ int s[256];
  int t = threadIdx.x;
  int own = (t < nb) ? partial[t] : 0;
  s[t] = own; __syncthreads();
  for (int o = 1; o < 256; o <<= 1) {
    int v = (t >= o) ? s[t - o] : 0;
    __syncthreads();
    s[t] += v;
    __syncthreads();
  }
  if (t < nb) partial[t] = s[t] - own;  // exclusive
}

__global__ __launch_bounds__(256) void k_base(const int* __restrict__ cnt,
                                              const int* __restrict__ partial, int N,
                                              int* __restrict__ base,
                                              int* __restrict__ cursor) {
  __shared__ int s[256];
  int t = threadIdx.x;
  int i0 = blockIdx.x * SCAN_CHUNK + t * 4;
  int v[4]; int sum = 0;
#pragma unroll
  for (int k = 0; k < 4; ++k) { int i = i0 + k; v[k] = (i < N) ? cnt[i] : 0; sum += v[k]; }
  s[t] = sum; __syncthreads();
  for (int o = 1; o < 256; o <<= 1) {
    int x = (t >= o) ? s[t - o] : 0;
    __syncthreads();
    s[t] += x;
    __syncthreads();
  }
  int off = partial[blockIdx.x] + (s[t] - sum);
#pragma unroll
  for (int k = 0; k < 4; ++k) {
    int i = i0 + k;
    if (i < N) { base[i] = off; cursor[i] = off; off += v[k]; }
  }
}

// ---------------------------------------------------------------------------
// Fill CSR: entry[pos] = {src, norm}; cursor holds next free absolute slot.
__global__ __launch_bounds__(256) void k_fill(const void* eidx, long long E,
                                              const float* __restrict__ dinv,
                                              int* __restrict__ cursor,
                                              int2* __restrict__ entry,
                                              const int* __restrict__ flag) {
  long long e = (long long)blockIdx.x * 256 + threadIdx.x;
  if (e >= E) return;
  int f = *flag;
  int r = load_idx(eidx, e, f);
  int c = load_idx(eidx, E + e, f);
  int pos = atomicAdd(&cursor[c], 1);
  float nm = dinv[r] * dinv[c];
  entry[pos] = make_int2(r, __float_as_int(nm));
}

// ---------------------------------------------------------------------------
// xw1 = x @ W1   ([N,128] x [128,64]), register-tiled.
// Block: 256 threads -> 64 rows x 64 cols; each thread a 4x4 tile.
// W1 in LDS (32 KB); x read from global (L1-broadcast across the 16
// j-groups that share a row group). Inner step: 4 global dwordx4 +
// 4 ds_read_b128 + 64 v_fma per thread -> VALU-bound.
__global__ __launch_bounds__(256) void k_gemm1(const float* __restrict__ x,
                                               const float* __restrict__ W1,
                                               float* __restrict__ xw1, int N) {
  __shared__ float ws[IN_DIM * HID_DIM];  // [k][j], same layout as W1
  {
    const float4* src = (const float4*)W1;
    float4* dst = (float4*)ws;
    for (int i = threadIdx.x; i < IN_DIM * HID_DIM / 4; i += 256) dst[i] = src[i];
  }
  __syncthreads();

  const int rg = threadIdx.x >> 4;         // 0..15  row group
  const int jg = threadIdx.x & 15;         // 0..15  col group
  const int r0 = blockIdx.x * 64 + rg * 4; // first of 4 rows
  const int j0 = jg * 4;                   // first of 4 cols

  // clamp row base so OOB threads still load valid memory; stores guarded
  int rc[4];
#pragma unroll
  for (int d = 0; d < 4; ++d) { int r = r0 + d; rc[d] = r < N ? r : N - 1; }

  float acc[4][4];
#pragma unroll
  for (int d = 0; d < 4; ++d)
#pragma unroll
    for (int q = 0; q < 4; ++q) acc[d][q] = 0.f;

#pragma unroll 2
  for (int k4 = 0; k4 < IN_DIM / 4; ++k4) {
    float4 xv[4];
#pragma unroll
    for (int d = 0; d < 4; ++d)
      xv[d] = *(const float4*)(x + (size_t)rc[d] * IN_DIM + 4 * k4);
    float4 wv[4];
#pragma unroll
    for (int q = 0; q < 4; ++q)
      wv[q] = *(const float4*)(ws + (4 * k4 + q) * HID_DIM + j0);
#pragma unroll
    for (int d = 0; d < 4; ++d) {
      acc[d][0] += xv[d].x * wv[0].x + xv[d].y * wv[1].x + xv[d].z * wv[2].x + xv[d].w * wv[3].x;
      acc[d][1] += xv[d].x * wv[0].y + xv[d].y * wv[1].y + xv[d].z * wv[2].y + xv[d].w * wv[3].y;
      acc[d][2] += xv[d].x * wv[0].z + xv[d].y * wv[1].z + xv[d].z * wv[2].z + xv[d].w * wv[3].z;
      acc[d][3] += xv[d].x * wv[0].w + xv[d].y * wv[1].w + xv[d].z * wv[2].w + xv[d].w * wv[3].w;
    }
  }

#pragma unroll
  for (int d = 0; d < 4; ++d) {
    int r = r0 + d;
    if (r < N) {
      float4 v = make_float4(acc[d][0], acc[d][1], acc[d][2], acc[d][3]);
      *(float4*)(xw1 + (size_t)r * HID_DIM + j0) = v;
    }
  }
}

// ---------------------------------------------------------------------------
// gather layer 1 + relu + GEMM2 fused.
// 4 nodes per 256-thread block; 64 lanes per node (one per hidden dim).
// Epilogue: h staged in LDS, 32 threads/node compute h @ W2 -> xw2.
__global__ __launch_bounds__(256) void k_gather1(const int2* __restrict__ entry,
                                                 const int* __restrict__ base,
                                                 const int* __restrict__ cnt,
                                                 const float* __restrict__ dinv,
                                                 const float* __restrict__ xw1,
                                                 const float* __restrict__ b1,
                                                 const float* __restrict__ W2,
                                                 float* __restrict__ xw2, int N) {
  __shared__ float w2s[HID_DIM * OUT_DIM];  // 8 KB
  __shared__ float hs[4][HID_DIM];          // 1 KB
  for (int i = threadIdx.x; i < HID_DIM * OUT_DIM; i += 256) w2s[i] = W2[i];

  const int nl   = threadIdx.x >> 6;
  const int j    = threadIdx.x & 63;
  const int node = blockIdx.x * 4 + nl;

  float hv = 0.f;
  if (node < N) {
    int st  = base[node];
    int len = cnt[node];
    float a0 = 0.f, a1 = 0.f;
    int i = 0;
    for (; i + 1 < len; i += 2) {
      int2 e0 = entry[st + i];
      int2 e1 = entry[st + i + 1];
      a0 += __int_as_float(e0.y) * xw1[(size_t)e0.x * HID_DIM + j];
      a1 += __int_as_float(e1.y) * xw1[(size_t)e1.x * HID_DIM + j];
    }
    if (i < len) {
      int2 e0 = entry[st + i];
      a0 += __int_as_float(e0.y) * xw1[(size_t)e0.x * HID_DIM + j];
    }
    float dv = dinv[node];
    hv = a0 + a1 + dv * dv * xw1[(size_t)node * HID_DIM + j] + b1[j];
    hv = hv > 0.f ? hv : 0.f;
  }
  hs[nl][j] = hv;
  __syncthreads();

  if (threadIdx.x < 128) {
    int n2l   = threadIdx.x >> 5;
    int k     = threadIdx.x & 31;
    int node2 = blockIdx.x * 4 + n2l;
    if (node2 < N) {
      float acc = 0.f;
#pragma unroll
      for (int jj = 0; jj < HID_DIM; ++jj)
        acc += hs[n2l][jj] * w2s[jj * OUT_DIM + k];
      xw2[(size_t)node2 * OUT_DIM + k] = acc;
    }
  }
}

// ---------------------------------------------------------------------------
// gather layer 2 + relu, writes d_out directly. 8 nodes/block, 32 lanes/node.
__global__ __launch_bounds__(256) void k_gather2(const int2* __restrict__ entry,
                                                 const int* __restrict__ base,
                                                 const int* __restrict__ cnt,
                                                 const float* __restrict__ dinv,
                                                 const float* __restrict__ xw2,
                                                 const float* __restrict__ b2,
                                                 float* __restrict__ out, int N) {
  const int nl   = threadIdx.x >> 5;
  const int j    = threadIdx.x & 31;
  const int node = blockIdx.x * 8 + nl;
  if (node >= N) return;
  int st  = base[node];
  int len = cnt[node];
  float a0 = 0.f, a1 = 0.f;
  int i = 0;
  for (; i + 1 < len; i += 2) {
    int2 e0 = entry[st + i];
    int2 e1 = entry[st + i + 1];
    a0 += __int_as_float(e0.y) * xw2[(size_t)e0.x * OUT_DIM + j];
    a1 += __int_as_float(e1.y) * xw2[(size_t)e1.x * OUT_DIM + j];
  }
  if (i < len) {
    int2 e0 = entry[st + i];
    a0 += __int_as_float(e0.y) * xw2[(size_t)e0.x * OUT_DIM + j];
  }
  float dv = dinv[node];
  float v = a0 + a1 + dv * dv * xw2[(size_t)node * OUT_DIM + j] + b2[j];
  out[(size_t)node * OUT_DIM + j] = v > 0.f ? v : 0.f;
}

// ---------------------------------------------------------------------------
static inline size_t align256(size_t x) { return (x + 255) & ~(size_t)255; }

extern "C" void kernel_launch(void* const* d_in, const int* in_sizes, int n_in,
                              void* d_out, int out_size, void* d_ws, size_t ws_size,
                              hipStream_t stream) {
  const float* x   = (const float*)d_in[0];
  const float* W1  = (const float*)d_in[1];
  const float* b1  = (const float*)d_in[2];
  const float* W2  = (const float*)d_in[3];
  const float* b2  = (const float*)d_in[4];
  const void*  eidx = d_in[5];

  const int  N = in_sizes[0] / IN_DIM;             // 100000
  const long long E = (long long)in_sizes[5] / 2;  // 1600000
  const int  nb = (N + SCAN_CHUNK - 1) / SCAN_CHUNK;  // 98 (<=256)

  char* ws = (char*)d_ws;
  size_t off = 0;
  int*   flag    = (int*)(ws + off);   off += align256(sizeof(int));
  int*   cnt     = (int*)(ws + off);   off += align256((size_t)N * 4);
  float* dinv    = (float*)(ws + off); off += align256((size_t)N * 4);
  int*   base    = (int*)(ws + off);   off += align256((size_t)N * 4);
  int*   cursor  = (int*)(ws + off);   off += align256((size_t)N * 4);
  int*   partial = (int*)(ws + off);   off += align256(256 * 4);
  int2*  entry   = (int2*)(ws + off);  off += align256((size_t)E * 8);
  float* xw1     = (float*)(ws + off); off += align256((size_t)N * HID_DIM * 4);
  float* xw2     = (float*)(ws + off); off += align256((size_t)N * OUT_DIM * 4);
  float* outf    = (float*)d_out;

  hipMemsetAsync(cnt, 0, (size_t)N * 4, stream);

  k_detect<<<1, 1, 0, stream>>>((const unsigned long long*)eidx, E, (long long)N, flag);

  k_count<<<(int)((E + 255) / 256), 256, 0, stream>>>(eidx, E, cnt, flag);
  k_dinv<<<(N + 255) / 256, 256, 0, stream>>>(cnt, dinv, N);

  k_blksum<<<nb, 256, 0, stream>>>(cnt, N, partial);
  k_scanpartial<<<1, 256, 0, stream>>>(partial, nb);
  k_base<<<nb, 256, 0, stream>>>(cnt, partial, N, base, cursor);

  k_fill<<<(int)((E + 255) / 256), 256, 0, stream>>>(eidx, E, dinv, cursor, entry, flag);

  k_gemm1<<<(N + 63) / 64, 256, 0, stream>>>(x, W1, xw1, N);

  k_gather1<<<(N + 3) / 4, 256, 0, stream>>>(entry, base, cnt, dinv, xw1, b1, W2, xw2, N);

  k_gather2<<<(N + 7) / 8, 256, 0, stream>>>(entry, base, cnt, dinv, xw2, b2, outf, N);
}

// Round 5
// 345.021 us; speedup vs baseline: 2.4487x; 1.0650x over previous
//
#include <hip/hip_runtime.h>

#define IN_DIM  128
#define HID_DIM 64
#define OUT_DIM 32
#define SCAN_CHUNK 1024   // elements per scan block (256 thr x 4)

// ---------------------------------------------------------------------------
// pack two f32 -> (bf16,bf16) in one u32, round-to-nearest-even
__device__ __forceinline__ unsigned pack_bf16(float a, float b) {
  unsigned ua = __float_as_uint(a), ub = __float_as_uint(b);
  ua += 0x7FFFu + ((ua >> 16) & 1u);
  ub += 0x7FFFu + ((ub >> 16) & 1u);
  return (ua >> 16) | (ub & 0xFFFF0000u);
}
__device__ __forceinline__ float bf_lo(unsigned v) { return __uint_as_float(v << 16); }
__device__ __forceinline__ float bf_hi(unsigned v) { return __uint_as_float(v & 0xFFFF0000u); }

// ---------------------------------------------------------------------------
// Detect whether edge_index is int64 or int32.
__global__ void k_detect(const unsigned long long* p, long long nwords,
                         long long nnodes, int* flag) {
  if (blockIdx.x == 0 && threadIdx.x == 0) {
    int ok = 1;
    int cnt = (int)(nwords < 64 ? nwords : 64);
    for (int i = 0; i < cnt; ++i) {
      if (p[i] >= (unsigned long long)nnodes) { ok = 0; break; }
    }
    *flag = ok;  // 1 = int64, 0 = int32
  }
}

__device__ __forceinline__ int load_idx(const void* p, long long i, int is64) {
  return is64 ? (int)((const long long*)p)[i] : ((const int*)p)[i];
}

// ---------------------------------------------------------------------------
// Histogram of destinations (self-loop handled analytically).
__global__ __launch_bounds__(256) void k_count(const void* eidx, long long E,
                                               int* __restrict__ cnt,
                                               const int* __restrict__ flag) {
  long long e = (long long)blockIdx.x * 256 + threadIdx.x;
  if (e >= E) return;
  int f = *flag;
  int c = load_idx(eidx, E + e, f);
  atomicAdd(&cnt[c], 1);
}

// ---------------------------------------------------------------------------
// 3-kernel exclusive scan of cnt[N] -> base[N]; also cursor=base, dinv.
__global__ __launch_bounds__(256) void k_blksum(const int* __restrict__ cnt, int N,
                                                int* __restrict__ partial) {
  __shared__ int s[256];
  int t = threadIdx.x;
  int i0 = blockIdx.x * SCAN_CHUNK + t * 4;
  int sum = 0;
#pragma unroll
  for (int k = 0; k < 4; ++k) { int i = i0 + k; if (i < N) sum += cnt[i]; }
  s[t] = sum; __syncthreads();
  for (int o = 128; o > 0; o >>= 1) { if (t < o) s[t] += s[t + o]; __syncthreads(); }
  if (t == 0) partial[blockIdx.x] = s[0];
}

__global__ __launch_bounds__(256) void k_scanpartial(int* __restrict__ partial, int nb) {
  __shared__ int s[256];
  int t = threadIdx.x;
  int own = (t < nb) ? partial[t] : 0;
  s[t] = own; __syncthreads();
  for (int o = 1; o < 256; o <<= 1) {
    int v = (t >= o) ? s[t - o] : 0;
    __syncthreads();
    s[t] += v;
    __syncthreads();
  }
  if (t < nb) partial[t] = s[t] - own;  // exclusive
}

__global__ __launch_bounds__(256) void k_base(const int* __restrict__ cnt,
                                              const int* __restrict__ partial, int N,
                                              int* __restrict__ base,
                                              int* __restrict__ cursor,
                                              float* __restrict__ dinv) {
  __shared__ int s[256];
  int t = threadIdx.x;
  int i0 = blockIdx.x * SCAN_CHUNK + t * 4;
  int v[4]; int sum = 0;
#pragma unroll
  for (int k = 0; k < 4; ++k) { int i = i0 + k; v[k] = (i < N) ? cnt[i] : 0; sum += v[k]; }
  s[t] = sum; __syncthreads();
  for (int o = 1; o < 256; o <<= 1) {
    int x = (t >= o) ? s[t - o] : 0;
    __syncthreads();
    s[t] += x;
    __syncthreads();
  }
  int off = partial[blockIdx.x] + (s[t] - sum);
#pragma unroll
  for (int k = 0; k < 4; ++k) {
    int i = i0 + k;
    if (i < N) {
      base[i] = off; cursor[i] = off; off += v[k];
      dinv[i] = rsqrtf((float)v[k] + 1.0f);
    }
  }
}

// ---------------------------------------------------------------------------
// Fill CSR: entry[pos] = src  (norm factorized out; see gemm1/gathers)
__global__ __launch_bounds__(256) void k_fill(const void* eidx, long long E,
                                              int* __restrict__ cursor,
                                              int* __restrict__ entry,
                                              const int* __restrict__ flag) {
  long long e = (long long)blockIdx.x * 256 + threadIdx.x;
  if (e >= E) return;
  int f = *flag;
  int r = load_idx(eidx, e, f);
  int c = load_idx(eidx, E + e, f);
  int pos = atomicAdd(&cursor[c], 1);
  entry[pos] = r;
}

// ---------------------------------------------------------------------------
// xw1b[r] = bf16( dinv[r] * (x[r] @ W1) )   packed 2-per-u32, [N][32] u32.
// Register-tiled: 256 thr -> 64 rows x 64 cols, 4x4 per thread.
__global__ __launch_bounds__(256) void k_gemm1(const float* __restrict__ x,
                                               const float* __restrict__ W1,
                                               const float* __restrict__ dinv,
                                               unsigned* __restrict__ xw1b, int N) {
  __shared__ float ws[IN_DIM * HID_DIM];  // [k][j], same layout as W1
  {
    const float4* src = (const float4*)W1;
    float4* dst = (float4*)ws;
    for (int i = threadIdx.x; i < IN_DIM * HID_DIM / 4; i += 256) dst[i] = src[i];
  }
  __syncthreads();

  const int rg = threadIdx.x >> 4;         // 0..15  row group
  const int jg = threadIdx.x & 15;         // 0..15  col group
  const int r0 = blockIdx.x * 64 + rg * 4;
  const int j0 = jg * 4;

  int rc[4];
#pragma unroll
  for (int d = 0; d < 4; ++d) { int r = r0 + d; rc[d] = r < N ? r : N - 1; }

  float acc[4][4];
#pragma unroll
  for (int d = 0; d < 4; ++d)
#pragma unroll
    for (int q = 0; q < 4; ++q) acc[d][q] = 0.f;

#pragma unroll 2
  for (int k4 = 0; k4 < IN_DIM / 4; ++k4) {
    float4 xv[4];
#pragma unroll
    for (int d = 0; d < 4; ++d)
      xv[d] = *(const float4*)(x + (size_t)rc[d] * IN_DIM + 4 * k4);
    float4 wv[4];
#pragma unroll
    for (int q = 0; q < 4; ++q)
      wv[q] = *(const float4*)(ws + (4 * k4 + q) * HID_DIM + j0);
#pragma unroll
    for (int d = 0; d < 4; ++d) {
      acc[d][0] += xv[d].x * wv[0].x + xv[d].y * wv[1].x + xv[d].z * wv[2].x + xv[d].w * wv[3].x;
      acc[d][1] += xv[d].x * wv[0].y + xv[d].y * wv[1].y + xv[d].z * wv[2].y + xv[d].w * wv[3].y;
      acc[d][2] += xv[d].x * wv[0].z + xv[d].y * wv[1].z + xv[d].z * wv[2].z + xv[d].w * wv[3].z;
      acc[d][3] += xv[d].x * wv[0].w + xv[d].y * wv[1].w + xv[d].z * wv[2].w + xv[d].w * wv[3].w;
    }
  }

#pragma unroll
  for (int d = 0; d < 4; ++d) {
    int r = r0 + d;
    if (r < N) {
      float dv = dinv[r];
      uint2 pv;
      pv.x = pack_bf16(dv * acc[d][0], dv * acc[d][1]);
      pv.y = pack_bf16(dv * acc[d][2], dv * acc[d][3]);
      *(uint2*)(xw1b + (size_t)r * (HID_DIM / 2) + 2 * jg) = pv;
    }
  }
}

// ---------------------------------------------------------------------------
// gather layer 1 + relu + GEMM2 fused.
// Phase 1: 8 nodes/block, 32 lanes/node, lane owns dims (2*lane, 2*lane+1).
//   h = dinv[c] * (sum of gathered pre-scaled rows + self row) + b1, relu.
// Phase 2: 16 thr/node compute xw2 = h @ W2, scale by dinv, pack bf16.
__global__ __launch_bounds__(256) void k_gather1(const int* __restrict__ entry,
                                                 const int* __restrict__ base,
                                                 const int* __restrict__ cnt,
                                                 const float* __restrict__ dinv,
                                                 const unsigned* __restrict__ xw1b,
                                                 const float* __restrict__ b1,
                                                 const float* __restrict__ W2,
                                                 unsigned* __restrict__ xw2b, int N) {
  __shared__ float w2s[HID_DIM * OUT_DIM];  // 8 KB, [j][k] row-major like W2
  __shared__ float hs[8][HID_DIM + 1];      // +1 pad: conflict-free epilogue
  __shared__ float dvs[8];
  for (int i = threadIdx.x; i < HID_DIM * OUT_DIM; i += 256) w2s[i] = W2[i];

  const int nl   = threadIdx.x >> 5;   // 0..7
  const int lane = threadIdx.x & 31;
  const int node = blockIdx.x * 8 + nl;

  if (node < N) {
    int st  = base[node];
    int len = cnt[node];
    float a0l = 0.f, a0h = 0.f, a1l = 0.f, a1h = 0.f;
    int i = 0;
    for (; i + 1 < len; i += 2) {
      int s0 = entry[st + i];
      int s1 = entry[st + i + 1];
      unsigned v0 = xw1b[(size_t)s0 * (HID_DIM / 2) + lane];
      unsigned v1 = xw1b[(size_t)s1 * (HID_DIM / 2) + lane];
      a0l += bf_lo(v0); a0h += bf_hi(v0);
      a1l += bf_lo(v1); a1h += bf_hi(v1);
    }
    if (i < len) {
      unsigned v0 = xw1b[(size_t)entry[st + i] * (HID_DIM / 2) + lane];
      a0l += bf_lo(v0); a0h += bf_hi(v0);
    }
    unsigned vs = xw1b[(size_t)node * (HID_DIM / 2) + lane];  // self-loop
    a0l += bf_lo(vs); a0h += bf_hi(vs);
    float dv = dinv[node];
    float2 bb = *(const float2*)(b1 + 2 * lane);
    float hl = dv * (a0l + a1l) + bb.x;
    float hh = dv * (a0h + a1h) + bb.y;
    hs[nl][2 * lane]     = hl > 0.f ? hl : 0.f;
    hs[nl][2 * lane + 1] = hh > 0.f ? hh : 0.f;
    if (lane == 0) dvs[nl] = dv;
  }
  __syncthreads();

  if (threadIdx.x < 128) {
    int g = threadIdx.x >> 4;        // node slot 0..7
    int k = threadIdx.x & 15;        // output dim pair
    int node2 = blockIdx.x * 8 + g;
    if (node2 < N) {
      float acc0 = 0.f, acc1 = 0.f;
#pragma unroll
      for (int jj = 0; jj < HID_DIM; ++jj) {
        float hv = hs[g][jj];
        float2 w = *(const float2*)(w2s + jj * OUT_DIM + 2 * k);
        acc0 += hv * w.x;
        acc1 += hv * w.y;
      }
      float dv = dvs[g];
      xw2b[(size_t)node2 * (OUT_DIM / 2) + k] = pack_bf16(dv * acc0, dv * acc1);
    }
  }
}

// ---------------------------------------------------------------------------
// gather layer 2 + relu -> d_out (f32). 16 nodes/block, 16 lanes/node.
__global__ __launch_bounds__(256) void k_gather2(const int* __restrict__ entry,
                                                 const int* __restrict__ base,
                                                 const int* __restrict__ cnt,
                                                 const float* __restrict__ dinv,
                                                 const unsigned* __restrict__ xw2b,
                                                 const float* __restrict__ b2,
                                                 float* __restrict__ out, int N) {
  const int nl   = threadIdx.x >> 4;   // 0..15
  const int lane = threadIdx.x & 15;
  const int node = blockIdx.x * 16 + nl;
  if (node >= N) return;
  int st  = base[node];
  int len = cnt[node];
  float a0l = 0.f, a0h = 0.f, a1l = 0.f, a1h = 0.f;
  int i = 0;
  for (; i + 1 < len; i += 2) {
    int s0 = entry[st + i];
    int s1 = entry[st + i + 1];
    unsigned v0 = xw2b[(size_t)s0 * (OUT_DIM / 2) + lane];
    unsigned v1 = xw2b[(size_t)s1 * (OUT_DIM / 2) + lane];
    a0l += bf_lo(v0); a0h += bf_hi(v0);
    a1l += bf_lo(v1); a1h += bf_hi(v1);
  }
  if (i < len) {
    unsigned v0 = xw2b[(size_t)entry[st + i] * (OUT_DIM / 2) + lane];
    a0l += bf_lo(v0); a0h += bf_hi(v0);
  }
  unsigned vs = xw2b[(size_t)node * (OUT_DIM / 2) + lane];  // self-loop
  a0l += bf_lo(vs); a0h += bf_hi(vs);
  float dv = dinv[node];
  float2 bb = *(const float2*)(b2 + 2 * lane);
  float v0 = dv * (a0l + a1l) + bb.x;
  float v1 = dv * (a0h + a1h) + bb.y;
  float2 res;
  res.x = v0 > 0.f ? v0 : 0.f;
  res.y = v1 > 0.f ? v1 : 0.f;
  *(float2*)(out + (size_t)node * OUT_DIM + 2 * lane) = res;
}

// ---------------------------------------------------------------------------
static inline size_t align256(size_t x) { return (x + 255) & ~(size_t)255; }

extern "C" void kernel_launch(void* const* d_in, const int* in_sizes, int n_in,
                              void* d_out, int out_size, void* d_ws, size_t ws_size,
                              hipStream_t stream) {
  const float* x   = (const float*)d_in[0];
  const float* W1  = (const float*)d_in[1];
  const float* b1  = (const float*)d_in[2];
  const float* W2  = (const float*)d_in[3];
  const float* b2  = (const float*)d_in[4];
  const void*  eidx = d_in[5];

  const int  N = in_sizes[0] / IN_DIM;                // 100000
  const long long E = (long long)in_sizes[5] / 2;     // 1600000
  const int  nb = (N + SCAN_CHUNK - 1) / SCAN_CHUNK;  // 98 (<=256)

  char* ws = (char*)d_ws;
  size_t off = 0;
  int*      flag    = (int*)(ws + off);      off += align256(sizeof(int));
  int*      cnt     = (int*)(ws + off);      off += align256((size_t)N * 4);
  float*    dinv    = (float*)(ws + off);    off += align256((size_t)N * 4);
  int*      base    = (int*)(ws + off);      off += align256((size_t)N * 4);
  int*      cursor  = (int*)(ws + off);      off += align256((size_t)N * 4);
  int*      partial = (int*)(ws + off);      off += align256(256 * 4);
  int*      entry   = (int*)(ws + off);      off += align256((size_t)E * 4);
  unsigned* xw1b    = (unsigned*)(ws + off); off += align256((size_t)N * (HID_DIM / 2) * 4);
  unsigned* xw2b    = (unsigned*)(ws + off); off += align256((size_t)N * (OUT_DIM / 2) * 4);
  float*    outf    = (float*)d_out;

  hipMemsetAsync(cnt, 0, (size_t)N * 4, stream);

  k_detect<<<1, 1, 0, stream>>>((const unsigned long long*)eidx, E, (long long)N, flag);

  k_count<<<(int)((E + 255) / 256), 256, 0, stream>>>(eidx, E, cnt, flag);

  k_blksum<<<nb, 256, 0, stream>>>(cnt, N, partial);
  k_scanpartial<<<1, 256, 0, stream>>>(partial, nb);
  k_base<<<nb, 256, 0, stream>>>(cnt, partial, N, base, cursor, dinv);

  k_fill<<<(int)((E + 255) / 256), 256, 0, stream>>>(eidx, E, cursor, entry, flag);

  k_gemm1<<<(N + 63) / 64, 256, 0, stream>>>(x, W1, dinv, xw1b, N);

  k_gather1<<<(N + 7) / 8, 256, 0, stream>>>(entry, base, cnt, dinv, xw1b, b1, W2, xw2b, N);

  k_gather2<<<(N + 15) / 16, 256, 0, stream>>>(entry, base, cnt, dinv, xw2b, b2, outf, N);
}

// Round 6
// 205.103 us; speedup vs baseline: 4.1192x; 1.6822x over previous
//
#include <hip/hip_runtime.h>

#define IN_DIM  128
#define HID_DIM 64
#define OUT_DIM 32
#define BPN   256     // nodes per destination bin (dstLocal fits 8 bits)
#define CHUNK 4096    // edges per partition block (256 thr x 16)

// ---------------------------------------------------------------------------
// pack two f32 -> (bf16,bf16) in one u32, round-to-nearest-even
__device__ __forceinline__ unsigned pack_bf16(float a, float b) {
  unsigned ua = __float_as_uint(a), ub = __float_as_uint(b);
  ua += 0x7FFFu + ((ua >> 16) & 1u);
  ub += 0x7FFFu + ((ub >> 16) & 1u);
  return (ua >> 16) | (ub & 0xFFFF0000u);
}
__device__ __forceinline__ float bf_lo(unsigned v) { return __uint_as_float(v << 16); }
__device__ __forceinline__ float bf_hi(unsigned v) { return __uint_as_float(v & 0xFFFF0000u); }

// ---------------------------------------------------------------------------
// Detect whether edge_index is int64 or int32.
__global__ void k_detect(const unsigned long long* p, long long nwords,
                         long long nnodes, int* flag) {
  if (blockIdx.x == 0 && threadIdx.x == 0) {
    int ok = 1;
    int cnt = (int)(nwords < 64 ? nwords : 64);
    for (int i = 0; i < cnt; ++i) {
      if (p[i] >= (unsigned long long)nnodes) { ok = 0; break; }
    }
    *flag = ok;  // 1 = int64, 0 = int32
  }
}

__device__ __forceinline__ int load_idx(const void* p, long long i, int is64) {
  return is64 ? (int)((const long long*)p)[i] : ((const int*)p)[i];
}

// ---------------------------------------------------------------------------
// P1: per-bin edge counts via per-block LDS histogram (~153k global atomics).
__global__ __launch_bounds__(256) void k_p1(const void* eidx, long long E,
                                            int* __restrict__ binCnt,
                                            const int* __restrict__ flag, int nbin) {
  __shared__ int hist[512];
  for (int i = threadIdx.x; i < nbin; i += 256) hist[i] = 0;
  __syncthreads();
  int f = *flag;
  long long b0 = (long long)blockIdx.x * CHUNK;
#pragma unroll
  for (int i = 0; i < CHUNK / 256; ++i) {
    long long e = b0 + i * 256 + threadIdx.x;
    if (e < E) atomicAdd(&hist[load_idx(eidx, E + e, f) >> 8], 1);
  }
  __syncthreads();
  for (int i = threadIdx.x; i < nbin; i += 256)
    if (hist[i]) atomicAdd(&binCnt[i], hist[i]);
}

// exclusive scan of binCnt -> binBase, binCursor   (nbin <= 512)
__global__ __launch_bounds__(512) void k_scanbins(const int* __restrict__ binCnt,
                                                  int* __restrict__ binBase,
                                                  int* __restrict__ binCursor, int nbin) {
  __shared__ int s[512];
  int t = threadIdx.x;
  int own = (t < nbin) ? binCnt[t] : 0;
  s[t] = own; __syncthreads();
  for (int o = 1; o < 512; o <<= 1) {
    int v = (t >= o) ? s[t - o] : 0;
    __syncthreads();
    s[t] += v;
    __syncthreads();
  }
  if (t < nbin) { int ex = s[t] - own; binBase[t] = ex; binCursor[t] = ex; }
}

// P2: scatter edges into bin-contiguous regions, packed {dstLocal<<17 | src}.
// Per (block,bin) one reservation atomic; ranks via LDS; writes land in runs.
__global__ __launch_bounds__(256) void k_p2(const void* eidx, long long E,
                                            int* __restrict__ binCursor,
                                            unsigned* __restrict__ entry1,
                                            const int* __restrict__ flag, int nbin) {
  __shared__ int hist[512];
  __shared__ int basel[512];
  for (int i = threadIdx.x; i < nbin; i += 256) hist[i] = 0;
  __syncthreads();
  int f = *flag;
  long long b0 = (long long)blockIdx.x * CHUNK;
#pragma unroll
  for (int i = 0; i < CHUNK / 256; ++i) {
    long long e = b0 + i * 256 + threadIdx.x;
    if (e < E) atomicAdd(&hist[load_idx(eidx, E + e, f) >> 8], 1);
  }
  __syncthreads();
  for (int i = threadIdx.x; i < nbin; i += 256) {
    int h = hist[i];
    basel[i] = h ? atomicAdd(&binCursor[i], h) : 0;
  }
  __syncthreads();
  for (int i = threadIdx.x; i < nbin; i += 256) hist[i] = 0;
  __syncthreads();
#pragma unroll
  for (int i = 0; i < CHUNK / 256; ++i) {
    long long e = b0 + i * 256 + threadIdx.x;
    if (e < E) {
      int r = load_idx(eidx, e, f);
      int c = load_idx(eidx, E + e, f);
      int bin = c >> 8;
      int rk = atomicAdd(&hist[bin], 1);
      entry1[basel[bin] + rk] = ((unsigned)(c & 255) << 17) | (unsigned)r;
    }
  }
}

// P3: one block per bin -> per-node CSR (entry2), base/cnt/dinv dense.
__global__ __launch_bounds__(256) void k_p3(const unsigned* __restrict__ entry1,
                                            const int* __restrict__ binBase,
                                            const int* __restrict__ binCnt,
                                            int* __restrict__ entry2,
                                            int* __restrict__ base,
                                            int* __restrict__ cnt,
                                            float* __restrict__ dinv, int N) {
  __shared__ int hist[BPN];
  __shared__ int off[BPN];
  __shared__ int s[BPN];
  int t = threadIdx.x;
  int b = blockIdx.x;
  int lo = binBase[b];
  int hi = lo + binCnt[b];
  int n0 = b * BPN;
  hist[t] = 0;
  __syncthreads();
  for (int i = lo + t; i < hi; i += 256)
    atomicAdd(&hist[entry1[i] >> 17], 1);
  __syncthreads();
  int own = hist[t];
  s[t] = own; __syncthreads();
  for (int o = 1; o < 256; o <<= 1) {
    int v = (t >= o) ? s[t - o] : 0;
    __syncthreads();
    s[t] += v;
    __syncthreads();
  }
  int node = n0 + t;
  int ex = lo + s[t] - own;   // exclusive prefix within bin, absolute slot
  if (node < N) {
    base[node] = ex;
    cnt[node]  = own;
    dinv[node] = rsqrtf((float)own + 1.0f);
  }
  off[t] = ex;
  __syncthreads();
  for (int i = lo + t; i < hi; i += 256) {
    unsigned v = entry1[i];
    int pos = atomicAdd(&off[v >> 17], 1);
    entry2[pos] = (int)(v & 0x1FFFFu);
  }
}

// ---------------------------------------------------------------------------
// xw1b[r] = bf16( dinv[r] * (x[r] @ W1) )   packed 2-per-u32, [N][32] u32.
__global__ __launch_bounds__(256) void k_gemm1(const float* __restrict__ x,
                                               const float* __restrict__ W1,
                                               const float* __restrict__ dinv,
                                               unsigned* __restrict__ xw1b, int N) {
  __shared__ float ws[IN_DIM * HID_DIM];  // [k][j], same layout as W1
  {
    const float4* src = (const float4*)W1;
    float4* dst = (float4*)ws;
    for (int i = threadIdx.x; i < IN_DIM * HID_DIM / 4; i += 256) dst[i] = src[i];
  }
  __syncthreads();

  const int rg = threadIdx.x >> 4;
  const int jg = threadIdx.x & 15;
  const int r0 = blockIdx.x * 64 + rg * 4;
  const int j0 = jg * 4;

  int rc[4];
#pragma unroll
  for (int d = 0; d < 4; ++d) { int r = r0 + d; rc[d] = r < N ? r : N - 1; }

  float acc[4][4];
#pragma unroll
  for (int d = 0; d < 4; ++d)
#pragma unroll
    for (int q = 0; q < 4; ++q) acc[d][q] = 0.f;

#pragma unroll 2
  for (int k4 = 0; k4 < IN_DIM / 4; ++k4) {
    float4 xv[4];
#pragma unroll
    for (int d = 0; d < 4; ++d)
      xv[d] = *(const float4*)(x + (size_t)rc[d] * IN_DIM + 4 * k4);
    float4 wv[4];
#pragma unroll
    for (int q = 0; q < 4; ++q)
      wv[q] = *(const float4*)(ws + (4 * k4 + q) * HID_DIM + j0);
#pragma unroll
    for (int d = 0; d < 4; ++d) {
      acc[d][0] += xv[d].x * wv[0].x + xv[d].y * wv[1].x + xv[d].z * wv[2].x + xv[d].w * wv[3].x;
      acc[d][1] += xv[d].x * wv[0].y + xv[d].y * wv[1].y + xv[d].z * wv[2].y + xv[d].w * wv[3].y;
      acc[d][2] += xv[d].x * wv[0].z + xv[d].y * wv[1].z + xv[d].z * wv[2].z + xv[d].w * wv[3].z;
      acc[d][3] += xv[d].x * wv[0].w + xv[d].y * wv[1].w + xv[d].z * wv[2].w + xv[d].w * wv[3].w;
    }
  }

#pragma unroll
  for (int d = 0; d < 4; ++d) {
    int r = r0 + d;
    if (r < N) {
      float dv = dinv[r];
      uint2 pv;
      pv.x = pack_bf16(dv * acc[d][0], dv * acc[d][1]);
      pv.y = pack_bf16(dv * acc[d][2], dv * acc[d][3]);
      *(uint2*)(xw1b + (size_t)r * (HID_DIM / 2) + 2 * jg) = pv;
    }
  }
}

// ---------------------------------------------------------------------------
// gather layer 1 + relu + GEMM2 fused.
__global__ __launch_bounds__(256) void k_gather1(const int* __restrict__ entry,
                                                 const int* __restrict__ base,
                                                 const int* __restrict__ cnt,
                                                 const float* __restrict__ dinv,
                                                 const unsigned* __restrict__ xw1b,
                                                 const float* __restrict__ b1,
                                                 const float* __restrict__ W2,
                                                 unsigned* __restrict__ xw2b, int N) {
  __shared__ float w2s[HID_DIM * OUT_DIM];  // 8 KB
  __shared__ float hs[8][HID_DIM + 1];
  __shared__ float dvs[8];
  for (int i = threadIdx.x; i < HID_DIM * OUT_DIM; i += 256) w2s[i] = W2[i];

  const int nl   = threadIdx.x >> 5;
  const int lane = threadIdx.x & 31;
  const int node = blockIdx.x * 8 + nl;

  if (node < N) {
    int st  = base[node];
    int len = cnt[node];
    float a0l = 0.f, a0h = 0.f, a1l = 0.f, a1h = 0.f;
    int i = 0;
    for (; i + 1 < len; i += 2) {
      int s0 = entry[st + i];
      int s1 = entry[st + i + 1];
      unsigned v0 = xw1b[(size_t)s0 * (HID_DIM / 2) + lane];
      unsigned v1 = xw1b[(size_t)s1 * (HID_DIM / 2) + lane];
      a0l += bf_lo(v0); a0h += bf_hi(v0);
      a1l += bf_lo(v1); a1h += bf_hi(v1);
    }
    if (i < len) {
      unsigned v0 = xw1b[(size_t)entry[st + i] * (HID_DIM / 2) + lane];
      a0l += bf_lo(v0); a0h += bf_hi(v0);
    }
    unsigned vs = xw1b[(size_t)node * (HID_DIM / 2) + lane];  // self-loop
    a0l += bf_lo(vs); a0h += bf_hi(vs);
    float dv = dinv[node];
    float2 bb = *(const float2*)(b1 + 2 * lane);
    float hl = dv * (a0l + a1l) + bb.x;
    float hh = dv * (a0h + a1h) + bb.y;
    hs[nl][2 * lane]     = hl > 0.f ? hl : 0.f;
    hs[nl][2 * lane + 1] = hh > 0.f ? hh : 0.f;
    if (lane == 0) dvs[nl] = dv;
  }
  __syncthreads();

  if (threadIdx.x < 128) {
    int g = threadIdx.x >> 4;
    int k = threadIdx.x & 15;
    int node2 = blockIdx.x * 8 + g;
    if (node2 < N) {
      float acc0 = 0.f, acc1 = 0.f;
#pragma unroll
      for (int jj = 0; jj < HID_DIM; ++jj) {
        float hv = hs[g][jj];
        float2 w = *(const float2*)(w2s + jj * OUT_DIM + 2 * k);
        acc0 += hv * w.x;
        acc1 += hv * w.y;
      }
      float dv = dvs[g];
      xw2b[(size_t)node2 * (OUT_DIM / 2) + k] = pack_bf16(dv * acc0, dv * acc1);
    }
  }
}

// ---------------------------------------------------------------------------
// gather layer 2 + relu -> d_out (f32). 16 nodes/block, 16 lanes/node.
__global__ __launch_bounds__(256) void k_gather2(const int* __restrict__ entry,
                                                 const int* __restrict__ base,
                                                 const int* __restrict__ cnt,
                                                 const float* __restrict__ dinv,
                                                 const unsigned* __restrict__ xw2b,
                                                 const float* __restrict__ b2,
                                                 float* __restrict__ out, int N) {
  const int nl   = threadIdx.x >> 4;
  const int lane = threadIdx.x & 15;
  const int node = blockIdx.x * 16 + nl;
  if (node >= N) return;
  int st  = base[node];
  int len = cnt[node];
  float a0l = 0.f, a0h = 0.f, a1l = 0.f, a1h = 0.f;
  int i = 0;
  for (; i + 1 < len; i += 2) {
    int s0 = entry[st + i];
    int s1 = entry[st + i + 1];
    unsigned v0 = xw2b[(size_t)s0 * (OUT_DIM / 2) + lane];
    unsigned v1 = xw2b[(size_t)s1 * (OUT_DIM / 2) + lane];
    a0l += bf_lo(v0); a0h += bf_hi(v0);
    a1l += bf_lo(v1); a1h += bf_hi(v1);
  }
  if (i < len) {
    unsigned v0 = xw2b[(size_t)entry[st + i] * (OUT_DIM / 2) + lane];
    a0l += bf_lo(v0); a0h += bf_hi(v0);
  }
  unsigned vs = xw2b[(size_t)node * (OUT_DIM / 2) + lane];  // self-loop
  a0l += bf_lo(vs); a0h += bf_hi(vs);
  float dv = dinv[node];
  float2 bb = *(const float2*)(b2 + 2 * lane);
  float v0 = dv * (a0l + a1l) + bb.x;
  float v1 = dv * (a0h + a1h) + bb.y;
  float2 res;
  res.x = v0 > 0.f ? v0 : 0.f;
  res.y = v1 > 0.f ? v1 : 0.f;
  *(float2*)(out + (size_t)node * OUT_DIM + 2 * lane) = res;
}

// ---------------------------------------------------------------------------
static inline size_t align256(size_t x) { return (x + 255) & ~(size_t)255; }

extern "C" void kernel_launch(void* const* d_in, const int* in_sizes, int n_in,
                              void* d_out, int out_size, void* d_ws, size_t ws_size,
                              hipStream_t stream) {
  const float* x   = (const float*)d_in[0];
  const float* W1  = (const float*)d_in[1];
  const float* b1  = (const float*)d_in[2];
  const float* W2  = (const float*)d_in[3];
  const float* b2  = (const float*)d_in[4];
  const void*  eidx = d_in[5];

  const int  N = in_sizes[0] / IN_DIM;             // 100000 (< 2^17 for packing)
  const long long E = (long long)in_sizes[5] / 2;  // 1600000
  const int  nbin = (N + BPN - 1) / BPN;           // 391 (<= 512)
  const int  np   = (int)((E + CHUNK - 1) / CHUNK);

  char* ws = (char*)d_ws;
  size_t off = 0;
  int*      flag      = (int*)(ws + off);      off += align256(sizeof(int));
  int*      cnt       = (int*)(ws + off);      off += align256((size_t)N * 4);
  float*    dinv      = (float*)(ws + off);    off += align256((size_t)N * 4);
  int*      base      = (int*)(ws + off);      off += align256((size_t)N * 4);
  int*      binCnt    = (int*)(ws + off);      off += align256(512 * 4);
  int*      binBase   = (int*)(ws + off);      off += align256(512 * 4);
  int*      binCursor = (int*)(ws + off);      off += align256(512 * 4);
  unsigned* entry1    = (unsigned*)(ws + off); off += align256((size_t)E * 4);
  int*      entry2    = (int*)(ws + off);      off += align256((size_t)E * 4);
  unsigned* xw1b      = (unsigned*)(ws + off); off += align256((size_t)N * (HID_DIM / 2) * 4);
  unsigned* xw2b      = (unsigned*)(ws + off); off += align256((size_t)N * (OUT_DIM / 2) * 4);
  float*    outf      = (float*)d_out;

  hipMemsetAsync(binCnt, 0, 512 * 4, stream);

  k_detect<<<1, 1, 0, stream>>>((const unsigned long long*)eidx, E, (long long)N, flag);

  k_p1<<<np, 256, 0, stream>>>(eidx, E, binCnt, flag, nbin);
  k_scanbins<<<1, 512, 0, stream>>>(binCnt, binBase, binCursor, nbin);
  k_p2<<<np, 256, 0, stream>>>(eidx, E, binCursor, entry1, flag, nbin);
  k_p3<<<nbin, 256, 0, stream>>>(entry1, binBase, binCnt, entry2, base, cnt, dinv, N);

  k_gemm1<<<(N + 63) / 64, 256, 0, stream>>>(x, W1, dinv, xw1b, N);

  k_gather1<<<(N + 7) / 8, 256, 0, stream>>>(entry2, base, cnt, dinv, xw1b, b1, W2, xw2b, N);

  k_gather2<<<(N + 15) / 16, 256, 0, stream>>>(entry2, base, cnt, dinv, xw2b, b2, outf, N);
}

// Round 7
// 179.555 us; speedup vs baseline: 4.7053x; 1.1423x over previous
//
#include <hip/hip_runtime.h>

#define IN_DIM  128
#define HID_DIM 64
#define OUT_DIM 32
#define BPN   256     // nodes per destination bin (dstLocal fits 8 bits)
#define CHUNK 4096    // edges per partition block (256 thr x 16)

// ---------------------------------------------------------------------------
// pack two f32 -> (bf16,bf16) in one u32, round-to-nearest-even
__device__ __forceinline__ unsigned pack_bf16(float a, float b) {
  unsigned ua = __float_as_uint(a), ub = __float_as_uint(b);
  ua += 0x7FFFu + ((ua >> 16) & 1u);
  ub += 0x7FFFu + ((ub >> 16) & 1u);
  return (ua >> 16) | (ub & 0xFFFF0000u);
}
__device__ __forceinline__ float bf_lo(unsigned v) { return __uint_as_float(v << 16); }
__device__ __forceinline__ float bf_hi(unsigned v) { return __uint_as_float(v & 0xFFFF0000u); }

// ---------------------------------------------------------------------------
// Detect whether edge_index is int64 or int32 (one wave, parallel probe).
__global__ void k_detect(const unsigned long long* p, long long nwords,
                         long long nnodes, int* flag) {
  int t = threadIdx.x;                       // 64 threads
  long long cnt = nwords < 64 ? nwords : 64;
  bool ok = true;
  if (t < cnt) ok = p[t] < (unsigned long long)nnodes;
  unsigned long long ball = __ballot(ok);
  if (t == 0) *flag = (ball == ~0ULL) ? 1 : 0;  // 1 = int64, 0 = int32
}

__device__ __forceinline__ int load_idx(const void* p, long long i, int is64) {
  return is64 ? (int)((const long long*)p)[i] : ((const int*)p)[i];
}

// ---------------------------------------------------------------------------
// P1: per-bin edge counts via per-block LDS histogram.
__global__ __launch_bounds__(256) void k_p1(const void* eidx, long long E,
                                            int* __restrict__ binCnt,
                                            const int* __restrict__ flag, int nbin) {
  __shared__ int hist[512];
  for (int i = threadIdx.x; i < nbin; i += 256) hist[i] = 0;
  __syncthreads();
  int f = *flag;
  long long b0 = (long long)blockIdx.x * CHUNK;
#pragma unroll
  for (int i = 0; i < CHUNK / 256; ++i) {
    long long e = b0 + i * 256 + threadIdx.x;
    if (e < E) atomicAdd(&hist[load_idx(eidx, E + e, f) >> 8], 1);
  }
  __syncthreads();
  for (int i = threadIdx.x; i < nbin; i += 256)
    if (hist[i]) atomicAdd(&binCnt[i], hist[i]);
}

// exclusive scan of binCnt -> binBase, binCursor (nbin <= 512);
// spare threads zero the dummy rows (row N) of xw1b/xw2b.
__global__ __launch_bounds__(512) void k_scanbins(const int* __restrict__ binCnt,
                                                  int* __restrict__ binBase,
                                                  int* __restrict__ binCursor, int nbin,
                                                  unsigned* __restrict__ xw1b,
                                                  unsigned* __restrict__ xw2b, int N) {
  __shared__ int s[512];
  int t = threadIdx.x;
  if (t < HID_DIM / 2) xw1b[(size_t)N * (HID_DIM / 2) + t] = 0;
  else if (t < HID_DIM / 2 + OUT_DIM / 2)
    xw2b[(size_t)N * (OUT_DIM / 2) + (t - HID_DIM / 2)] = 0;
  int own = (t < nbin) ? binCnt[t] : 0;
  s[t] = own; __syncthreads();
  for (int o = 1; o < 512; o <<= 1) {
    int v = (t >= o) ? s[t - o] : 0;
    __syncthreads();
    s[t] += v;
    __syncthreads();
  }
  if (t < nbin) { int ex = s[t] - own; binBase[t] = ex; binCursor[t] = ex; }
}

// P2: scatter edges into bin-contiguous regions, packed {dstLocal<<17 | src}.
__global__ __launch_bounds__(256) void k_p2(const void* eidx, long long E,
                                            int* __restrict__ binCursor,
                                            unsigned* __restrict__ entry1,
                                            const int* __restrict__ flag, int nbin) {
  __shared__ int hist[512];
  __shared__ int basel[512];
  for (int i = threadIdx.x; i < nbin; i += 256) hist[i] = 0;
  __syncthreads();
  int f = *flag;
  long long b0 = (long long)blockIdx.x * CHUNK;
#pragma unroll
  for (int i = 0; i < CHUNK / 256; ++i) {
    long long e = b0 + i * 256 + threadIdx.x;
    if (e < E) atomicAdd(&hist[load_idx(eidx, E + e, f) >> 8], 1);
  }
  __syncthreads();
  for (int i = threadIdx.x; i < nbin; i += 256) {
    int h = hist[i];
    basel[i] = h ? atomicAdd(&binCursor[i], h) : 0;
  }
  __syncthreads();
  for (int i = threadIdx.x; i < nbin; i += 256) hist[i] = 0;
  __syncthreads();
#pragma unroll
  for (int i = 0; i < CHUNK / 256; ++i) {
    long long e = b0 + i * 256 + threadIdx.x;
    if (e < E) {
      int r = load_idx(eidx, e, f);
      int c = load_idx(eidx, E + e, f);
      int bin = c >> 8;
      int rk = atomicAdd(&hist[bin], 1);
      entry1[basel[bin] + rk] = ((unsigned)(c & 255) << 17) | (unsigned)r;
    }
  }
}

// P3: one block per bin -> per-node CSR with 4-aligned runs (pad = dummy N).
__global__ __launch_bounds__(256) void k_p3(const unsigned* __restrict__ entry1,
                                            const int* __restrict__ binBase,
                                            const int* __restrict__ binCnt,
                                            int* __restrict__ entry2,
                                            int* __restrict__ base,
                                            int* __restrict__ cnt,
                                            float* __restrict__ dinv, int N) {
  __shared__ int hist[BPN];
  __shared__ int off[BPN];
  __shared__ int s[BPN];
  int t = threadIdx.x;
  int b = blockIdx.x;
  int lo = binBase[b];
  int hi = lo + binCnt[b];
  int pBB = ((lo + 3) & ~3) + 4 * BPN * b;   // padded, 4-aligned bin base
  int n0 = b * BPN;
  hist[t] = 0;
  __syncthreads();
  for (int i = lo + t; i < hi; i += 256)
    atomicAdd(&hist[entry1[i] >> 17], 1);
  __syncthreads();
  int own  = hist[t];
  int own4 = (own + 3) & ~3;
  s[t] = own4; __syncthreads();
  for (int o = 1; o < 256; o <<= 1) {
    int v = (t >= o) ? s[t - o] : 0;
    __syncthreads();
    s[t] += v;
    __syncthreads();
  }
  int node = n0 + t;
  int ex = pBB + (s[t] - own4);              // 4-aligned absolute slot
  if (node < N) {
    base[node] = ex;
    cnt[node]  = own;
    dinv[node] = rsqrtf((float)own + 1.0f);
    for (int q = own; q < own4; ++q) entry2[ex + q] = N;  // dummy pads
  }
  off[t] = ex;
  __syncthreads();
  for (int i = lo + t; i < hi; i += 256) {
    unsigned v = entry1[i];
    int pos = atomicAdd(&off[v >> 17], 1);
    entry2[pos] = (int)(v & 0x1FFFFu);
  }
}

// ---------------------------------------------------------------------------
// xw1b[r] = bf16( dinv[r] * (x[r] @ W1) )   packed 2-per-u32, [N][32] u32.
__global__ __launch_bounds__(256) void k_gemm1(const float* __restrict__ x,
                                               const float* __restrict__ W1,
                                               const float* __restrict__ dinv,
                                               unsigned* __restrict__ xw1b, int N) {
  __shared__ float ws[IN_DIM * HID_DIM];
  {
    const float4* src = (const float4*)W1;
    float4* dst = (float4*)ws;
    for (int i = threadIdx.x; i < IN_DIM * HID_DIM / 4; i += 256) dst[i] = src[i];
  }
  __syncthreads();

  const int rg = threadIdx.x >> 4;
  const int jg = threadIdx.x & 15;
  const int r0 = blockIdx.x * 64 + rg * 4;
  const int j0 = jg * 4;

  int rc[4];
#pragma unroll
  for (int d = 0; d < 4; ++d) { int r = r0 + d; rc[d] = r < N ? r : N - 1; }

  float acc[4][4];
#pragma unroll
  for (int d = 0; d < 4; ++d)
#pragma unroll
    for (int q = 0; q < 4; ++q) acc[d][q] = 0.f;

#pragma unroll 2
  for (int k4 = 0; k4 < IN_DIM / 4; ++k4) {
    float4 xv[4];
#pragma unroll
    for (int d = 0; d < 4; ++d)
      xv[d] = *(const float4*)(x + (size_t)rc[d] * IN_DIM + 4 * k4);
    float4 wv[4];
#pragma unroll
    for (int q = 0; q < 4; ++q)
      wv[q] = *(const float4*)(ws + (4 * k4 + q) * HID_DIM + j0);
#pragma unroll
    for (int d = 0; d < 4; ++d) {
      acc[d][0] += xv[d].x * wv[0].x + xv[d].y * wv[1].x + xv[d].z * wv[2].x + xv[d].w * wv[3].x;
      acc[d][1] += xv[d].x * wv[0].y + xv[d].y * wv[1].y + xv[d].z * wv[2].y + xv[d].w * wv[3].y;
      acc[d][2] += xv[d].x * wv[0].z + xv[d].y * wv[1].z + xv[d].z * wv[2].z + xv[d].w * wv[3].z;
      acc[d][3] += xv[d].x * wv[0].w + xv[d].y * wv[1].w + xv[d].z * wv[2].w + xv[d].w * wv[3].w;
    }
  }

#pragma unroll
  for (int d = 0; d < 4; ++d) {
    int r = r0 + d;
    if (r < N) {
      float dv = dinv[r];
      uint2 pv;
      pv.x = pack_bf16(dv * acc[d][0], dv * acc[d][1]);
      pv.y = pack_bf16(dv * acc[d][2], dv * acc[d][3]);
      *(uint2*)(xw1b + (size_t)r * (HID_DIM / 2) + 2 * jg) = pv;
    }
  }
}

// ---------------------------------------------------------------------------
// gather layer 1 + relu + GEMM2 fused. int4 index loads, 4-deep payload MLP.
__global__ __launch_bounds__(256) void k_gather1(const int* __restrict__ entry,
                                                 const int* __restrict__ base,
                                                 const int* __restrict__ cnt,
                                                 const float* __restrict__ dinv,
                                                 const unsigned* __restrict__ xw1b,
                                                 const float* __restrict__ b1,
                                                 const float* __restrict__ W2,
                                                 unsigned* __restrict__ xw2b, int N) {
  __shared__ float w2s[HID_DIM * OUT_DIM];  // 8 KB
  __shared__ float hs[8][HID_DIM + 1];
  __shared__ float dvs[8];
  for (int i = threadIdx.x; i < HID_DIM * OUT_DIM; i += 256) w2s[i] = W2[i];

  const int nl   = threadIdx.x >> 5;
  const int lane = threadIdx.x & 31;
  const int node = blockIdx.x * 8 + nl;

  if (node < N) {
    int st = base[node];
    int it = (cnt[node] + 3) >> 2;
    float a0l = 0.f, a0h = 0.f, a1l = 0.f, a1h = 0.f;
    float a2l = 0.f, a2h = 0.f, a3l = 0.f, a3h = 0.f;
    for (int i = 0; i < it; ++i) {
      int4 e4 = *(const int4*)(entry + st + 4 * i);     // wave-broadcast
      unsigned v0 = xw1b[(size_t)e4.x * (HID_DIM / 2) + lane];
      unsigned v1 = xw1b[(size_t)e4.y * (HID_DIM / 2) + lane];
      unsigned v2 = xw1b[(size_t)e4.z * (HID_DIM / 2) + lane];
      unsigned v3 = xw1b[(size_t)e4.w * (HID_DIM / 2) + lane];
      a0l += bf_lo(v0); a0h += bf_hi(v0);
      a1l += bf_lo(v1); a1h += bf_hi(v1);
      a2l += bf_lo(v2); a2h += bf_hi(v2);
      a3l += bf_lo(v3); a3h += bf_hi(v3);
    }
    unsigned vs = xw1b[(size_t)node * (HID_DIM / 2) + lane];  // self-loop
    float dv = dinv[node];
    float2 bb = *(const float2*)(b1 + 2 * lane);
    float hl = dv * ((a0l + a1l) + (a2l + a3l) + bf_lo(vs)) + bb.x;
    float hh = dv * ((a0h + a1h) + (a2h + a3h) + bf_hi(vs)) + bb.y;
    hs[nl][2 * lane]     = hl > 0.f ? hl : 0.f;
    hs[nl][2 * lane + 1] = hh > 0.f ? hh : 0.f;
    if (lane == 0) dvs[nl] = dv;
  }
  __syncthreads();

  if (threadIdx.x < 128) {
    int g = threadIdx.x >> 4;
    int k = threadIdx.x & 15;
    int node2 = blockIdx.x * 8 + g;
    if (node2 < N) {
      float acc0 = 0.f, acc1 = 0.f;
#pragma unroll
      for (int jj = 0; jj < HID_DIM; ++jj) {
        float hv = hs[g][jj];
        float2 w = *(const float2*)(w2s + jj * OUT_DIM + 2 * k);
        acc0 += hv * w.x;
        acc1 += hv * w.y;
      }
      float dv = dvs[g];
      xw2b[(size_t)node2 * (OUT_DIM / 2) + k] = pack_bf16(dv * acc0, dv * acc1);
    }
  }
}

// ---------------------------------------------------------------------------
// gather layer 2 + relu -> d_out. 16 nodes/block, 16 lanes/node, 4-deep MLP.
__global__ __launch_bounds__(256) void k_gather2(const int* __restrict__ entry,
                                                 const int* __restrict__ base,
                                                 const int* __restrict__ cnt,
                                                 const float* __restrict__ dinv,
                                                 const unsigned* __restrict__ xw2b,
                                                 const float* __restrict__ b2,
                                                 float* __restrict__ out, int N) {
  const int nl   = threadIdx.x >> 4;
  const int lane = threadIdx.x & 15;
  const int node = blockIdx.x * 16 + nl;
  if (node >= N) return;
  int st = base[node];
  int it = (cnt[node] + 3) >> 2;
  float a0l = 0.f, a0h = 0.f, a1l = 0.f, a1h = 0.f;
  float a2l = 0.f, a2h = 0.f, a3l = 0.f, a3h = 0.f;
  for (int i = 0; i < it; ++i) {
    int4 e4 = *(const int4*)(entry + st + 4 * i);
    unsigned v0 = xw2b[(size_t)e4.x * (OUT_DIM / 2) + lane];
    unsigned v1 = xw2b[(size_t)e4.y * (OUT_DIM / 2) + lane];
    unsigned v2 = xw2b[(size_t)e4.z * (OUT_DIM / 2) + lane];
    unsigned v3 = xw2b[(size_t)e4.w * (OUT_DIM / 2) + lane];
    a0l += bf_lo(v0); a0h += bf_hi(v0);
    a1l += bf_lo(v1); a1h += bf_hi(v1);
    a2l += bf_lo(v2); a2h += bf_hi(v2);
    a3l += bf_lo(v3); a3h += bf_hi(v3);
  }
  unsigned vs = xw2b[(size_t)node * (OUT_DIM / 2) + lane];  // self-loop
  float dv = dinv[node];
  float2 bb = *(const float2*)(b2 + 2 * lane);
  float v0 = dv * ((a0l + a1l) + (a2l + a3l) + bf_lo(vs)) + bb.x;
  float v1 = dv * ((a0h + a1h) + (a2h + a3h) + bf_hi(vs)) + bb.y;
  float2 res;
  res.x = v0 > 0.f ? v0 : 0.f;
  res.y = v1 > 0.f ? v1 : 0.f;
  *(float2*)(out + (size_t)node * OUT_DIM + 2 * lane) = res;
}

// ---------------------------------------------------------------------------
static inline size_t align256(size_t x) { return (x + 255) & ~(size_t)255; }

extern "C" void kernel_launch(void* const* d_in, const int* in_sizes, int n_in,
                              void* d_out, int out_size, void* d_ws, size_t ws_size,
                              hipStream_t stream) {
  const float* x   = (const float*)d_in[0];
  const float* W1  = (const float*)d_in[1];
  const float* b1  = (const float*)d_in[2];
  const float* W2  = (const float*)d_in[3];
  const float* b2  = (const float*)d_in[4];
  const void*  eidx = d_in[5];

  const int  N = in_sizes[0] / IN_DIM;             // 100000 (< 2^17 for packing)
  const long long E = (long long)in_sizes[5] / 2;  // 1600000
  const int  nbin = (N + BPN - 1) / BPN;           // 391 (<= 512)
  const int  np   = (int)((E + CHUNK - 1) / CHUNK);
  const size_t e2cap = (size_t)E + (size_t)4 * BPN * nbin + 64;

  char* ws = (char*)d_ws;
  size_t off = 0;
  int*      flag      = (int*)(ws + off);      off += align256(sizeof(int));
  int*      cnt       = (int*)(ws + off);      off += align256((size_t)N * 4);
  float*    dinv      = (float*)(ws + off);    off += align256((size_t)N * 4);
  int*      base      = (int*)(ws + off);      off += align256((size_t)N * 4);
  int*      binCnt    = (int*)(ws + off);      off += align256(512 * 4);
  int*      binBase   = (int*)(ws + off);      off += align256(512 * 4);
  int*      binCursor = (int*)(ws + off);      off += align256(512 * 4);
  unsigned* entry1    = (unsigned*)(ws + off); off += align256((size_t)E * 4);
  int*      entry2    = (int*)(ws + off);      off += align256(e2cap * 4);
  unsigned* xw1b      = (unsigned*)(ws + off); off += align256((size_t)(N + 1) * (HID_DIM / 2) * 4);
  unsigned* xw2b      = (unsigned*)(ws + off); off += align256((size_t)(N + 1) * (OUT_DIM / 2) * 4);
  float*    outf      = (float*)d_out;

  hipMemsetAsync(binCnt, 0, 512 * 4, stream);

  k_detect<<<1, 64, 0, stream>>>((const unsigned long long*)eidx, E, (long long)N, flag);

  k_p1<<<np, 256, 0, stream>>>(eidx, E, binCnt, flag, nbin);
  k_scanbins<<<1, 512, 0, stream>>>(binCnt, binBase, binCursor, nbin, xw1b, xw2b, N);
  k_p2<<<np, 256, 0, stream>>>(eidx, E, binCursor, entry1, flag, nbin);
  k_p3<<<nbin, 256, 0, stream>>>(entry1, binBase, binCnt, entry2, base, cnt, dinv, N);

  k_gemm1<<<(N + 63) / 64, 256, 0, stream>>>(x, W1, dinv, xw1b, N);

  k_gather1<<<(N + 7) / 8, 256, 0, stream>>>(entry2, base, cnt, dinv, xw1b, b1, W2, xw2b, N);

  k_gather2<<<(N + 15) / 16, 256, 0, stream>>>(entry2, base, cnt, dinv, xw2b, b2, outf, N);
}

// Round 8
// 165.304 us; speedup vs baseline: 5.1110x; 1.0862x over previous
//
#include <hip/hip_runtime.h>

#define IN_DIM  128
#define HID_DIM 64
#define OUT_DIM 32
#define BPN   256     // nodes per destination bin (dstLocal fits 8 bits)
#define CHUNK 4096    // edges per partition block (256 thr x 16)

// ---------------------------------------------------------------------------
// pack two f32 -> (bf16,bf16) in one u32, round-to-nearest-even
__device__ __forceinline__ unsigned pack_bf16(float a, float b) {
  unsigned ua = __float_as_uint(a), ub = __float_as_uint(b);
  ua += 0x7FFFu + ((ua >> 16) & 1u);
  ub += 0x7FFFu + ((ub >> 16) & 1u);
  return (ua >> 16) | (ub & 0xFFFF0000u);
}
__device__ __forceinline__ float bf_lo(unsigned v) { return __uint_as_float(v << 16); }
__device__ __forceinline__ float bf_hi(unsigned v) { return __uint_as_float(v & 0xFFFF0000u); }

__device__ __forceinline__ int load_idx(const void* p, long long i, int is64) {
  return is64 ? (int)((const long long*)p)[i] : ((const int*)p)[i];
}

// In-block dtype probe: first wave checks 64 u64 words; int32 data read as
// u64 packs two values -> >= N almost surely. Result broadcast via LDS.
__device__ __forceinline__ int block_detect(const void* eidx, long long E,
                                            long long N, int* sflag) {
  bool ok = true;
  long long cap = E < 64 ? E : 64;
  if (threadIdx.x < cap)
    ok = ((const unsigned long long*)eidx)[threadIdx.x] < (unsigned long long)N;
  unsigned long long ball = __ballot(ok);
  if (threadIdx.x == 0) *sflag = (ball == ~0ULL) ? 1 : 0;
  __syncthreads();
  return *sflag;
}

// ---------------------------------------------------------------------------
// P1: per-bin edge counts; 4 per-wave LDS histograms to cut atomic conflicts.
__global__ __launch_bounds__(256) void k_p1(const void* eidx, long long E,
                                            int* __restrict__ binCnt,
                                            long long N, int nbin) {
  __shared__ int hist[4 * 512];
  __shared__ int sflag;
  for (int i = threadIdx.x; i < 4 * 512; i += 256) hist[i] = 0;
  int f = block_detect(eidx, E, N, &sflag);   // includes __syncthreads
  int* h = hist + 512 * (threadIdx.x >> 6);
  long long b0 = (long long)blockIdx.x * CHUNK;
#pragma unroll
  for (int i = 0; i < CHUNK / 256; ++i) {
    long long e = b0 + i * 256 + threadIdx.x;
    if (e < E) atomicAdd(&h[load_idx(eidx, E + e, f) >> 8], 1);
  }
  __syncthreads();
  for (int i = threadIdx.x; i < nbin; i += 256) {
    int s = hist[i] + hist[512 + i] + hist[1024 + i] + hist[1536 + i];
    if (s) atomicAdd(&binCnt[i], s);
  }
}

// exclusive scan of binCnt -> binBase, binCursor (nbin <= 512);
// spare threads zero the dummy rows (row N) of xw1b/xw2b.
__global__ __launch_bounds__(512) void k_scanbins(const int* __restrict__ binCnt,
                                                  int* __restrict__ binBase,
                                                  int* __restrict__ binCursor, int nbin,
                                                  unsigned* __restrict__ xw1b,
                                                  unsigned* __restrict__ xw2b, int N) {
  __shared__ int s[512];
  int t = threadIdx.x;
  if (t < HID_DIM / 2) xw1b[(size_t)N * (HID_DIM / 2) + t] = 0;
  else if (t < HID_DIM / 2 + OUT_DIM / 2)
    xw2b[(size_t)N * (OUT_DIM / 2) + (t - HID_DIM / 2)] = 0;
  int own = (t < nbin) ? binCnt[t] : 0;
  s[t] = own; __syncthreads();
  for (int o = 1; o < 512; o <<= 1) {
    int v = (t >= o) ? s[t - o] : 0;
    __syncthreads();
    s[t] += v;
    __syncthreads();
  }
  if (t < nbin) { int ex = s[t] - own; binBase[t] = ex; binCursor[t] = ex; }
}

// P2: scatter edges into bin-contiguous regions, packed {dstLocal<<17 | src}.
__global__ __launch_bounds__(256) void k_p2(const void* eidx, long long E,
                                            int* __restrict__ binCursor,
                                            unsigned* __restrict__ entry1,
                                            long long N, int nbin) {
  __shared__ int hist[512];
  __shared__ int basel[512];
  __shared__ int sflag;
  for (int i = threadIdx.x; i < nbin; i += 256) hist[i] = 0;
  int f = block_detect(eidx, E, N, &sflag);
  long long b0 = (long long)blockIdx.x * CHUNK;
#pragma unroll
  for (int i = 0; i < CHUNK / 256; ++i) {
    long long e = b0 + i * 256 + threadIdx.x;
    if (e < E) atomicAdd(&hist[load_idx(eidx, E + e, f) >> 8], 1);
  }
  __syncthreads();
  for (int i = threadIdx.x; i < nbin; i += 256) {
    int h = hist[i];
    basel[i] = h ? atomicAdd(&binCursor[i], h) : 0;
  }
  __syncthreads();
  for (int i = threadIdx.x; i < nbin; i += 256) hist[i] = 0;
  __syncthreads();
#pragma unroll
  for (int i = 0; i < CHUNK / 256; ++i) {
    long long e = b0 + i * 256 + threadIdx.x;
    if (e < E) {
      int r = load_idx(eidx, e, f);
      int c = load_idx(eidx, E + e, f);
      int bin = c >> 8;
      int rk = atomicAdd(&hist[bin], 1);
      entry1[basel[bin] + rk] = ((unsigned)(c & 255) << 17) | (unsigned)r;
    }
  }
}

// P3: one block per bin -> per-node CSR with 4-aligned runs (pad = dummy N).
__global__ __launch_bounds__(256) void k_p3(const unsigned* __restrict__ entry1,
                                            const int* __restrict__ binBase,
                                            const int* __restrict__ binCnt,
                                            int* __restrict__ entry2,
                                            int* __restrict__ base,
                                            int* __restrict__ cnt,
                                            float* __restrict__ dinv, int N) {
  __shared__ int hist[BPN];
  __shared__ int off[BPN];
  __shared__ int s[BPN];
  int t = threadIdx.x;
  int b = blockIdx.x;
  int lo = binBase[b];
  int hi = lo + binCnt[b];
  int pBB = ((lo + 3) & ~3) + 4 * BPN * b;   // padded, 4-aligned bin base
  int n0 = b * BPN;
  hist[t] = 0;
  __syncthreads();
  for (int i = lo + t; i < hi; i += 256)
    atomicAdd(&hist[entry1[i] >> 17], 1);
  __syncthreads();
  int own  = hist[t];
  int own4 = (own + 3) & ~3;
  s[t] = own4; __syncthreads();
  for (int o = 1; o < 256; o <<= 1) {
    int v = (t >= o) ? s[t - o] : 0;
    __syncthreads();
    s[t] += v;
    __syncthreads();
  }
  int node = n0 + t;
  int ex = pBB + (s[t] - own4);              // 4-aligned absolute slot
  if (node < N) {
    base[node] = ex;
    cnt[node]  = own;
    dinv[node] = rsqrtf((float)own + 1.0f);
    for (int q = own; q < own4; ++q) entry2[ex + q] = N;  // dummy pads
  }
  off[t] = ex;
  __syncthreads();
  for (int i = lo + t; i < hi; i += 256) {
    unsigned v = entry1[i];
    int pos = atomicAdd(&off[v >> 17], 1);
    entry2[pos] = (int)(v & 0x1FFFFu);
  }
}

// ---------------------------------------------------------------------------
// xw1b[r] = bf16( dinv[r] * (x[r] @ W1) )   packed 2-per-u32, [N][32] u32.
__global__ __launch_bounds__(256) void k_gemm1(const float* __restrict__ x,
                                               const float* __restrict__ W1,
                                               const float* __restrict__ dinv,
                                               unsigned* __restrict__ xw1b, int N) {
  __shared__ float ws[IN_DIM * HID_DIM];
  {
    const float4* src = (const float4*)W1;
    float4* dst = (float4*)ws;
    for (int i = threadIdx.x; i < IN_DIM * HID_DIM / 4; i += 256) dst[i] = src[i];
  }
  __syncthreads();

  const int rg = threadIdx.x >> 4;
  const int jg = threadIdx.x & 15;
  const int r0 = blockIdx.x * 64 + rg * 4;
  const int j0 = jg * 4;

  int rc[4];
#pragma unroll
  for (int d = 0; d < 4; ++d) { int r = r0 + d; rc[d] = r < N ? r : N - 1; }

  float acc[4][4];
#pragma unroll
  for (int d = 0; d < 4; ++d)
#pragma unroll
    for (int q = 0; q < 4; ++q) acc[d][q] = 0.f;

#pragma unroll 2
  for (int k4 = 0; k4 < IN_DIM / 4; ++k4) {
    float4 xv[4];
#pragma unroll
    for (int d = 0; d < 4; ++d)
      xv[d] = *(const float4*)(x + (size_t)rc[d] * IN_DIM + 4 * k4);
    float4 wv[4];
#pragma unroll
    for (int q = 0; q < 4; ++q)
      wv[q] = *(const float4*)(ws + (4 * k4 + q) * HID_DIM + j0);
#pragma unroll
    for (int d = 0; d < 4; ++d) {
      acc[d][0] += xv[d].x * wv[0].x + xv[d].y * wv[1].x + xv[d].z * wv[2].x + xv[d].w * wv[3].x;
      acc[d][1] += xv[d].x * wv[0].y + xv[d].y * wv[1].y + xv[d].z * wv[2].y + xv[d].w * wv[3].y;
      acc[d][2] += xv[d].x * wv[0].z + xv[d].y * wv[1].z + xv[d].z * wv[2].z + xv[d].w * wv[3].z;
      acc[d][3] += xv[d].x * wv[0].w + xv[d].y * wv[1].w + xv[d].z * wv[2].w + xv[d].w * wv[3].w;
    }
  }

#pragma unroll
  for (int d = 0; d < 4; ++d) {
    int r = r0 + d;
    if (r < N) {
      float dv = dinv[r];
      uint2 pv;
      pv.x = pack_bf16(dv * acc[d][0], dv * acc[d][1]);
      pv.y = pack_bf16(dv * acc[d][2], dv * acc[d][3]);
      *(uint2*)(xw1b + (size_t)r * (HID_DIM / 2) + 2 * jg) = pv;
    }
  }
}

// ---------------------------------------------------------------------------
// gather layer 1 + relu + GEMM2, wave-self-contained (no inter-phase barrier).
// 16 nodes/block; each wave owns 4 nodes (16 lanes/node, dwordx2 payloads).
// Phase 2 (h @ W2) by the same wave: LDS ops in a wave are in-order.
__global__ __launch_bounds__(256) void k_gather1(const int* __restrict__ entry,
                                                 const int* __restrict__ base,
                                                 const int* __restrict__ cnt,
                                                 const float* __restrict__ dinv,
                                                 const uint2* __restrict__ xw1b2,
                                                 const float* __restrict__ b1,
                                                 const float* __restrict__ W2,
                                                 unsigned* __restrict__ xw2b, int N) {
  __shared__ float w2s[HID_DIM * OUT_DIM];  // 8 KB
  __shared__ float hs[16][68];              // row stride 272 B (16B-aligned)
  __shared__ float dvs[16];
  for (int i = threadIdx.x; i < HID_DIM * OUT_DIM; i += 256) w2s[i] = W2[i];
  __syncthreads();   // w2s ready; only barrier in the kernel

  const int wv   = threadIdx.x >> 6;   // wave 0..3
  const int ln   = threadIdx.x & 63;
  const int slot = wv * 4 + (ln >> 4); // node slot 0..15 (4 per wave)
  const int lane = ln & 15;            // lane owns dims 4*lane..4*lane+3
  const int node = blockIdx.x * 16 + slot;

  if (node < N) {
    int st = base[node];
    int it = (cnt[node] + 3) >> 2;
    float ax[4], ay[4], az[4], aw[4];
#pragma unroll
    for (int q = 0; q < 4; ++q) { ax[q] = ay[q] = az[q] = aw[q] = 0.f; }
    for (int i = 0; i < it; ++i) {
      int4 e4 = *(const int4*)(entry + st + 4 * i);
      uint2 v0 = xw1b2[(size_t)e4.x * 16 + lane];
      uint2 v1 = xw1b2[(size_t)e4.y * 16 + lane];
      uint2 v2 = xw1b2[(size_t)e4.z * 16 + lane];
      uint2 v3 = xw1b2[(size_t)e4.w * 16 + lane];
      ax[0] += bf_lo(v0.x); ay[0] += bf_hi(v0.x); az[0] += bf_lo(v0.y); aw[0] += bf_hi(v0.y);
      ax[1] += bf_lo(v1.x); ay[1] += bf_hi(v1.x); az[1] += bf_lo(v1.y); aw[1] += bf_hi(v1.y);
      ax[2] += bf_lo(v2.x); ay[2] += bf_hi(v2.x); az[2] += bf_lo(v2.y); aw[2] += bf_hi(v2.y);
      ax[3] += bf_lo(v3.x); ay[3] += bf_hi(v3.x); az[3] += bf_lo(v3.y); aw[3] += bf_hi(v3.y);
    }
    uint2 vs = xw1b2[(size_t)node * 16 + lane];  // self-loop
    float dv = dinv[node];
    float4 bb = *(const float4*)(b1 + 4 * lane);
    float h0 = dv * ((ax[0] + ax[1]) + (ax[2] + ax[3]) + bf_lo(vs.x)) + bb.x;
    float h1 = dv * ((ay[0] + ay[1]) + (ay[2] + ay[3]) + bf_hi(vs.x)) + bb.y;
    float h2 = dv * ((az[0] + az[1]) + (az[2] + az[3]) + bf_lo(vs.y)) + bb.z;
    float h3 = dv * ((aw[0] + aw[1]) + (aw[2] + aw[3]) + bf_hi(vs.y)) + bb.w;
    float4 hv;
    hv.x = h0 > 0.f ? h0 : 0.f;
    hv.y = h1 > 0.f ? h1 : 0.f;
    hv.z = h2 > 0.f ? h2 : 0.f;
    hv.w = h3 > 0.f ? h3 : 0.f;
    *(float4*)(&hs[slot][4 * lane]) = hv;
    if (lane == 0) dvs[slot] = dv;
  }
  __builtin_amdgcn_wave_barrier();  // keep compiler from reordering DS ops

  if (node < N) {
    float acc0 = 0.f, acc1 = 0.f;
#pragma unroll
    for (int jj = 0; jj < HID_DIM; ++jj) {
      float hv = hs[slot][jj];
      float2 w = *(const float2*)(w2s + jj * OUT_DIM + 2 * lane);
      acc0 += hv * w.x;
      acc1 += hv * w.y;
    }
    float dv = dvs[slot];
    xw2b[(size_t)node * (OUT_DIM / 2) + lane] = pack_bf16(dv * acc0, dv * acc1);
  }
}

// ---------------------------------------------------------------------------
// gather layer 2 + relu -> d_out. 32 nodes/block, 8 lanes/node, dwordx2.
__global__ __launch_bounds__(256) void k_gather2(const int* __restrict__ entry,
                                                 const int* __restrict__ base,
                                                 const int* __restrict__ cnt,
                                                 const float* __restrict__ dinv,
                                                 const uint2* __restrict__ xw2b2,
                                                 const float* __restrict__ b2,
                                                 float* __restrict__ out, int N) {
  const int nl   = threadIdx.x >> 3;   // 0..31
  const int lane = threadIdx.x & 7;    // lane owns dims 4*lane..4*lane+3
  const int node = blockIdx.x * 32 + nl;
  if (node >= N) return;
  int st = base[node];
  int it = (cnt[node] + 3) >> 2;
  float ax[4], ay[4], az[4], aw[4];
#pragma unroll
  for (int q = 0; q < 4; ++q) { ax[q] = ay[q] = az[q] = aw[q] = 0.f; }
  for (int i = 0; i < it; ++i) {
    int4 e4 = *(const int4*)(entry + st + 4 * i);
    uint2 v0 = xw2b2[(size_t)e4.x * 8 + lane];
    uint2 v1 = xw2b2[(size_t)e4.y * 8 + lane];
    uint2 v2 = xw2b2[(size_t)e4.z * 8 + lane];
    uint2 v3 = xw2b2[(size_t)e4.w * 8 + lane];
    ax[0] += bf_lo(v0.x); ay[0] += bf_hi(v0.x); az[0] += bf_lo(v0.y); aw[0] += bf_hi(v0.y);
    ax[1] += bf_lo(v1.x); ay[1] += bf_hi(v1.x); az[1] += bf_lo(v1.y); aw[1] += bf_hi(v1.y);
    ax[2] += bf_lo(v2.x); ay[2] += bf_hi(v2.x); az[2] += bf_lo(v2.y); aw[2] += bf_hi(v2.y);
    ax[3] += bf_lo(v3.x); ay[3] += bf_hi(v3.x); az[3] += bf_lo(v3.y); aw[3] += bf_hi(v3.y);
  }
  uint2 vs = xw2b2[(size_t)node * 8 + lane];  // self-loop
  float dv = dinv[node];
  float4 bb = *(const float4*)(b2 + 4 * lane);
  float v0 = dv * ((ax[0] + ax[1]) + (ax[2] + ax[3]) + bf_lo(vs.x)) + bb.x;
  float v1 = dv * ((ay[0] + ay[1]) + (ay[2] + ay[3]) + bf_hi(vs.x)) + bb.y;
  float v2 = dv * ((az[0] + az[1]) + (az[2] + az[3]) + bf_lo(vs.y)) + bb.z;
  float v3 = dv * ((aw[0] + aw[1]) + (aw[2] + aw[3]) + bf_hi(vs.y)) + bb.w;
  float4 res;
  res.x = v0 > 0.f ? v0 : 0.f;
  res.y = v1 > 0.f ? v1 : 0.f;
  res.z = v2 > 0.f ? v2 : 0.f;
  res.w = v3 > 0.f ? v3 : 0.f;
  *(float4*)(out + (size_t)node * OUT_DIM + 4 * lane) = res;
}

// ---------------------------------------------------------------------------
static inline size_t align256(size_t x) { return (x + 255) & ~(size_t)255; }

extern "C" void kernel_launch(void* const* d_in, const int* in_sizes, int n_in,
                              void* d_out, int out_size, void* d_ws, size_t ws_size,
                              hipStream_t stream) {
  const float* x   = (const float*)d_in[0];
  const float* W1  = (const float*)d_in[1];
  const float* b1  = (const float*)d_in[2];
  const float* W2  = (const float*)d_in[3];
  const float* b2  = (const float*)d_in[4];
  const void*  eidx = d_in[5];

  const int  N = in_sizes[0] / IN_DIM;             // 100000 (< 2^17 for packing)
  const long long E = (long long)in_sizes[5] / 2;  // 1600000
  const int  nbin = (N + BPN - 1) / BPN;           // 391 (<= 512)
  const int  np   = (int)((E + CHUNK - 1) / CHUNK);
  const size_t e2cap = (size_t)E + (size_t)4 * BPN * nbin + 64;

  char* ws = (char*)d_ws;
  size_t off = 0;
  int*      cnt       = (int*)(ws + off);      off += align256((size_t)N * 4);
  float*    dinv      = (float*)(ws + off);    off += align256((size_t)N * 4);
  int*      base      = (int*)(ws + off);      off += align256((size_t)N * 4);
  int*      binCnt    = (int*)(ws + off);      off += align256(512 * 4);
  int*      binBase   = (int*)(ws + off);      off += align256(512 * 4);
  int*      binCursor = (int*)(ws + off);      off += align256(512 * 4);
  unsigned* entry1    = (unsigned*)(ws + off); off += align256((size_t)E * 4);
  int*      entry2    = (int*)(ws + off);      off += align256(e2cap * 4);
  unsigned* xw1b      = (unsigned*)(ws + off); off += align256((size_t)(N + 1) * (HID_DIM / 2) * 4);
  unsigned* xw2b      = (unsigned*)(ws + off); off += align256((size_t)(N + 1) * (OUT_DIM / 2) * 4);
  float*    outf      = (float*)d_out;

  hipMemsetAsync(binCnt, 0, 512 * 4, stream);

  k_p1<<<np, 256, 0, stream>>>(eidx, E, binCnt, (long long)N, nbin);
  k_scanbins<<<1, 512, 0, stream>>>(binCnt, binBase, binCursor, nbin, xw1b, xw2b, N);
  k_p2<<<np, 256, 0, stream>>>(eidx, E, binCursor, entry1, (long long)N, nbin);
  k_p3<<<nbin, 256, 0, stream>>>(entry1, binBase, binCnt, entry2, base, cnt, dinv, N);

  k_gemm1<<<(N + 63) / 64, 256, 0, stream>>>(x, W1, dinv, xw1b, N);

  k_gather1<<<(N + 15) / 16, 256, 0, stream>>>(entry2, base, cnt, dinv,
                                               (const uint2*)xw1b, b1, W2, xw2b, N);

  k_gather2<<<(N + 31) / 32, 256, 0, stream>>>(entry2, base, cnt, dinv,
                                               (const uint2*)xw2b, b2, outf, N);
}